// Round 1
// baseline (996.765 us; speedup 1.0000x reference)
//
#include <hip/hip_runtime.h>
#include <hip/hip_bf16.h>
#include <math.h>

// Problem dims
#define BB 32
#define PP 384
#define HH 384
#define DD 512
// derived
#define NPH 12288          // B*P = B*H
#define SIM_B (384*384)    // 147456 per batch
#define EMB_B (384*512)    // 196608 per batch

// d_out offsets (floats)
#define OUT_LOGITS 0
#define OUT_PROBS 96
#define OUT_H2P 192
#define OUT_P2H (192 + 32*384*384)

// ws offsets (floats)
#define WS_PROJ_P 0L
#define WS_PROJ_H 6291456L
#define WS_SIM    12582912L
#define WS_SIMT   17301504L
#define WS_G      22020096L
// aliases
#define WS_ATT_H  WS_PROJ_P
#define WS_ATT_P  WS_PROJ_H
#define WS_CMP_P  WS_SIM
#define WS_CMP_H  WS_PROJ_P

#define BK 32
#define TILE 64
#define LDP 68

template<bool NT, bool RELU, bool BIAS, bool CONCAT>
__global__ __launch_bounds__(256) void gemm_kernel(
    const float* __restrict__ A, const float* __restrict__ A2,
    const float* __restrict__ Bm, const float* __restrict__ bias,
    float* __restrict__ C,
    int M, int N, int K, int K1,
    long aBatch, long bBatch, long cBatch,
    int lda, int ldb, int ldc)
{
    __shared__ float as_[BK * LDP];
    __shared__ float bs_[BK * LDP];
    const int tid = threadIdx.x;
    const int tx = tid & 15, ty = tid >> 4;
    const int m0 = blockIdx.y * TILE, n0 = blockIdx.x * TILE;
    const long z = blockIdx.z;
    const float* Ab = A + z * aBatch;
    const float* A2b = CONCAT ? (A2 + z * aBatch) : nullptr;
    const float* Bb = Bm + z * bBatch;
    float* Cb = C + z * cBatch;

    const int a_c4 = tid & 7, a_r = tid >> 3;    // 64-row x 32-k loader
    const int b_c4 = tid & 15, b_r = tid >> 4;   // 32-k x 64-col loader (NN)

    float acc[4][4] = {};

    for (int k0 = 0; k0 < K; k0 += BK) {
        // ---- load A tile (rows m, k contiguous) -> as_[k][m]
        const float* Asrc = Ab;
        int kk = k0;
        if (CONCAT && k0 >= K1) { Asrc = A2b; kk = k0 - K1; }
        {
            float4 v0 = *(const float4*)&Asrc[(long)(m0 + a_r) * lda + kk + a_c4 * 4];
            float4 v1 = *(const float4*)&Asrc[(long)(m0 + a_r + 32) * lda + kk + a_c4 * 4];
            const float* p0 = (const float*)&v0;
            const float* p1 = (const float*)&v1;
            #pragma unroll
            for (int i = 0; i < 4; i++) {
                as_[(a_c4 * 4 + i) * LDP + a_r]      = p0[i];
                as_[(a_c4 * 4 + i) * LDP + a_r + 32] = p1[i];
            }
        }
        // ---- load B tile
        if (NT) {
            // B rows = n, k contiguous -> bs_[k][n]
            float4 v0 = *(const float4*)&Bb[(long)(n0 + a_r) * ldb + k0 + a_c4 * 4];
            float4 v1 = *(const float4*)&Bb[(long)(n0 + a_r + 32) * ldb + k0 + a_c4 * 4];
            const float* p0 = (const float*)&v0;
            const float* p1 = (const float*)&v1;
            #pragma unroll
            for (int i = 0; i < 4; i++) {
                bs_[(a_c4 * 4 + i) * LDP + a_r]      = p0[i];
                bs_[(a_c4 * 4 + i) * LDP + a_r + 32] = p1[i];
            }
        } else {
            // B rows = k, n contiguous -> bs_[k][n]
            float4 v0 = *(const float4*)&Bb[(long)(k0 + b_r) * ldb + n0 + b_c4 * 4];
            float4 v1 = *(const float4*)&Bb[(long)(k0 + b_r + 16) * ldb + n0 + b_c4 * 4];
            *(float4*)&bs_[b_r * LDP + b_c4 * 4] = v0;
            *(float4*)&bs_[(b_r + 16) * LDP + b_c4 * 4] = v1;
        }
        __syncthreads();

        #pragma unroll
        for (int k = 0; k < BK; k++) {
            float4 a4 = *(const float4*)(as_ + k * LDP + ty * 4);
            float4 b4 = *(const float4*)(bs_ + k * LDP + tx * 4);
            float ar[4] = {a4.x, a4.y, a4.z, a4.w};
            float br[4] = {b4.x, b4.y, b4.z, b4.w};
            #pragma unroll
            for (int i = 0; i < 4; i++)
                #pragma unroll
                for (int j = 0; j < 4; j++)
                    acc[i][j] = fmaf(ar[i], br[j], acc[i][j]);
        }
        __syncthreads();
    }

    #pragma unroll
    for (int i = 0; i < 4; i++) {
        int row = m0 + ty * 4 + i;
        float4 v;
        float* vp = (float*)&v;
        #pragma unroll
        for (int j = 0; j < 4; j++) {
            float c = acc[i][j];
            if (BIAS) c += bias[n0 + tx * 4 + j];
            if (RELU) c = fmaxf(c, 0.f);
            vp[j] = c;
        }
        *(float4*)&Cb[(long)row * ldc + n0 + tx * 4] = v;
    }
}

// Batched 384x384 transpose
__global__ __launch_bounds__(256) void transpose_kernel(const float* __restrict__ in,
                                                        float* __restrict__ out)
{
    __shared__ float tile[32][33];
    const int b = blockIdx.z;
    const int x0 = blockIdx.x * 32, y0 = blockIdx.y * 32;
    const int tx = threadIdx.x, ty = threadIdx.y; // (32, 8)
    const float* src = in + (long)b * SIM_B;
    float* dst = out + (long)b * SIM_B;
    #pragma unroll
    for (int i = 0; i < 32; i += 8)
        tile[ty + i][tx] = src[(long)(y0 + ty + i) * 384 + x0 + tx];
    __syncthreads();
    #pragma unroll
    for (int i = 0; i < 32; i += 8)
        dst[(long)(x0 + ty + i) * 384 + y0 + tx] = tile[tx][ty + i];
}

// Masked softmax over rows of length 384. mask indexed [b][col].
// Matches AllenNLP masked_softmax (softmax(s*m), re-mask, renorm).
__global__ __launch_bounds__(384) void masked_softmax_kernel(
    const float* __restrict__ S, const int* __restrict__ mask,
    float* __restrict__ out)
{
    const int row = blockIdx.x;        // 0..B*384-1
    const int b = row / 384;
    const int t = threadIdx.x;         // 0..383
    __shared__ float redmax[6];
    __shared__ float redsum[6];

    float v = S[(long)row * 384 + t];
    int mm = mask[b * 384 + t];

    float x = mm ? v : -3.4e38f;
    #pragma unroll
    for (int o = 32; o > 0; o >>= 1) x = fmaxf(x, __shfl_xor(x, o, 64));
    int wid = t >> 6, lane = t & 63;
    if (lane == 0) redmax[wid] = x;
    __syncthreads();
    float mx = redmax[0];
    #pragma unroll
    for (int w = 1; w < 6; w++) mx = fmaxf(mx, redmax[w]);

    float e = mm ? expf(v - mx) : 0.f;
    float s = e;
    #pragma unroll
    for (int o = 32; o > 0; o >>= 1) s += __shfl_xor(s, o, 64);
    if (lane == 0) redsum[wid] = s;
    __syncthreads();
    float tot = 0.f;
    #pragma unroll
    for (int w = 0; w < 6; w++) tot += redsum[w];

    out[(long)row * 384 + t] = (tot > 0.f) ? e / tot : 0.f;
}

// compared[b][off+d] = sum_p cmp[b][p][d] * mask[b][p]
__global__ __launch_bounds__(128) void masked_sum_kernel(
    const float* __restrict__ cmp, const int* __restrict__ mask,
    float* __restrict__ G, int off)
{
    const int b = blockIdx.y;
    const int d = blockIdx.x * 128 + threadIdx.x; // 0..511
    float acc = 0.f;
    const float* base = cmp + (long)b * EMB_B + d;
    const int* mrow = mask + b * 384;
    for (int p = 0; p < 384; p++) {
        acc += base[(long)p * 512] * (float)mrow[p];
    }
    G[(long)b * 1024 + off + d] = acc;
}

// hidden = relu(agg @ W1 + b1); logits = hidden @ W2 + b2; probs = softmax
__global__ __launch_bounds__(256) void final_kernel(
    const float* __restrict__ G, const float* __restrict__ W1,
    const float* __restrict__ b1, const float* __restrict__ W2,
    const float* __restrict__ b2, float* __restrict__ out)
{
    const int b = blockIdx.x;
    const int t = threadIdx.x;
    __shared__ float g[1024];
    __shared__ float h[512];
    const float* grow = G + (long)b * 1024;
    for (int i = t; i < 1024; i += 256) g[i] = grow[i];
    __syncthreads();
    for (int j = t; j < 512; j += 256) {
        float acc = b1[j];
        for (int k = 0; k < 1024; k++) acc = fmaf(g[k], W1[(long)k * 512 + j], acc);
        h[j] = fmaxf(acc, 0.f);
    }
    __syncthreads();
    if (t == 0) {
        float l[3];
        #pragma unroll
        for (int c = 0; c < 3; c++) {
            float acc = b2[c];
            for (int j = 0; j < 512; j++) acc = fmaf(h[j], W2[j * 3 + c], acc);
            l[c] = acc;
        }
        float mx = fmaxf(l[0], fmaxf(l[1], l[2]));
        float e0 = expf(l[0] - mx), e1 = expf(l[1] - mx), e2 = expf(l[2] - mx);
        float s = e0 + e1 + e2;
        out[OUT_LOGITS + b * 3 + 0] = l[0];
        out[OUT_LOGITS + b * 3 + 1] = l[1];
        out[OUT_LOGITS + b * 3 + 2] = l[2];
        out[OUT_PROBS + b * 3 + 0] = e0 / s;
        out[OUT_PROBS + b * 3 + 1] = e1 / s;
        out[OUT_PROBS + b * 3 + 2] = e2 / s;
    }
}

extern "C" void kernel_launch(void* const* d_in, const int* in_sizes, int n_in,
                              void* d_out, int out_size, void* d_ws, size_t ws_size,
                              hipStream_t stream) {
    const float* emb_p = (const float*)d_in[0];
    const float* emb_h = (const float*)d_in[1];
    const int* pm = (const int*)d_in[2];
    const int* hm = (const int*)d_in[3];
    const float* Wa = (const float*)d_in[4];
    const float* ba = (const float*)d_in[5];
    const float* Wc = (const float*)d_in[6];
    const float* bc = (const float*)d_in[7];
    const float* W1 = (const float*)d_in[8];
    const float* b1 = (const float*)d_in[9];
    const float* W2 = (const float*)d_in[10];
    const float* b2 = (const float*)d_in[11];
    float* out = (float*)d_out;
    float* ws = (float*)d_ws;

    // 1,2: proj_p / proj_h = relu(emb @ Wa + ba)   [12288,512]x[512,512]
    gemm_kernel<false, true, true, false><<<dim3(8, 192, 1), 256, 0, stream>>>(
        emb_p, nullptr, Wa, ba, ws + WS_PROJ_P,
        NPH, 512, 512, 0, 0, 0, 0, 512, 512, 512);
    gemm_kernel<false, true, true, false><<<dim3(8, 192, 1), 256, 0, stream>>>(
        emb_h, nullptr, Wa, ba, ws + WS_PROJ_H,
        NPH, 512, 512, 0, 0, 0, 0, 512, 512, 512);

    // 3: sim[b,p,h] = proj_p . proj_h  (batched NT) [384,512]x[384,512]^T
    gemm_kernel<true, false, false, false><<<dim3(6, 6, 32), 256, 0, stream>>>(
        ws + WS_PROJ_P, nullptr, ws + WS_PROJ_H, nullptr, ws + WS_SIM,
        384, 384, 512, 0, EMB_B, EMB_B, SIM_B, 512, 512, 384);

    // 4: simT
    transpose_kernel<<<dim3(12, 12, 32), dim3(32, 8), 0, stream>>>(
        ws + WS_SIM, ws + WS_SIMT);

    // 5: p2h = masked_softmax(sim, hm) -> out
    masked_softmax_kernel<<<NPH, 384, 0, stream>>>(ws + WS_SIM, hm, out + OUT_P2H);
    // 6: h2p = masked_softmax(simT, pm) -> out
    masked_softmax_kernel<<<NPH, 384, 0, stream>>>(ws + WS_SIMT, pm, out + OUT_H2P);

    // 7: att_h[b,p,d] = p2h @ emb_h   (batched NN) [384,384]x[384,512]
    gemm_kernel<false, false, false, false><<<dim3(8, 6, 32), 256, 0, stream>>>(
        out + OUT_P2H, nullptr, emb_h, nullptr, ws + WS_ATT_H,
        384, 512, 384, 0, SIM_B, EMB_B, EMB_B, 384, 512, 512);
    // 8: att_p[b,h,d] = h2p @ emb_p
    gemm_kernel<false, false, false, false><<<dim3(8, 6, 32), 256, 0, stream>>>(
        out + OUT_H2P, nullptr, emb_p, nullptr, ws + WS_ATT_P,
        384, 512, 384, 0, SIM_B, EMB_B, EMB_B, 384, 512, 512);

    // 9: cmp_p = relu(concat(emb_p, att_h) @ Wc + bc)  [12288,1024]x[1024,512]
    gemm_kernel<false, true, true, true><<<dim3(8, 192, 1), 256, 0, stream>>>(
        emb_p, ws + WS_ATT_H, Wc, bc, ws + WS_CMP_P,
        NPH, 512, 1024, 512, 0, 0, 0, 512, 512, 512);
    // 10: compared_premise = sum_p cmp_p * pm -> G[:, 0:512]
    masked_sum_kernel<<<dim3(4, 32), 128, 0, stream>>>(ws + WS_CMP_P, pm, ws + WS_G, 0);

    // 11: cmp_h = relu(concat(emb_h, att_p) @ Wc + bc)
    gemm_kernel<false, true, true, true><<<dim3(8, 192, 1), 256, 0, stream>>>(
        emb_h, ws + WS_ATT_P, Wc, bc, ws + WS_CMP_H,
        NPH, 512, 1024, 512, 0, 0, 0, 512, 512, 512);
    // 12: compared_hypothesis -> G[:, 512:1024]
    masked_sum_kernel<<<dim3(4, 32), 128, 0, stream>>>(ws + WS_CMP_H, hm, ws + WS_G, 512);

    // 13: aggregate MLP + softmax
    final_kernel<<<32, 256, 0, stream>>>(ws + WS_G, W1, b1, W2, b2, out);
}

// Round 4
// 517.230 us; speedup vs baseline: 1.9271x; 1.9271x over previous
//
#include <hip/hip_runtime.h>
#include <hip/hip_bf16.h>
#include <math.h>

typedef __bf16 bf16_t;
typedef __bf16 bf16x8 __attribute__((ext_vector_type(8)));
typedef float f32x4 __attribute__((ext_vector_type(4)));

// Problem dims
#define NPH 12288          // B*P = B*H
#define SIM_B (384*384)
#define EMB_B (384*512)

// d_out offsets (floats)
#define OUT_LOGITS 0
#define OUT_PROBS 96
#define OUT_H2P 192
#define OUT_P2H (192 + 32*384*384)

// ws offsets (bytes)
#define OFF_WAT 0L
#define OFF_WCT 1048576L
#define OFF_P1  2097152L
#define OFF_P2  (OFF_P1 + 25165824L)
#define OFF_SIM (OFF_P2 + 25165824L)
#define OFF_G   (OFF_SIM + 18874368L)

#define BM 128
#define BN 128
#define BKK 32

#define M_SPLIT3 0
#define M_PLAIN  1
#define M_CONCAT 2

__device__ inline void gload16(const void* g, void* l) {
    __builtin_amdgcn_global_load_lds(
        (const __attribute__((address_space(1))) void*)g,
        (__attribute__((address_space(3))) void*)l, 16, 0, 0);
}

// Stage 16 consecutive f32 -> bf16 hi (and optionally lo) into LDS
template<bool SPLIT>
__device__ inline void stage_tile_f32(const float* __restrict__ s,
                                      bf16_t* hi, bf16_t* lo, int eoff)
{
    float xs[16];
    *(float4*)&xs[0]  = *(const float4*)(s);
    *(float4*)&xs[4]  = *(const float4*)(s + 4);
    *(float4*)&xs[8]  = *(const float4*)(s + 8);
    *(float4*)&xs[12] = *(const float4*)(s + 12);
    bf16x8 h0, h1, l0, l1;
    #pragma unroll
    for (int i = 0; i < 8; i++) {
        float x = xs[i];     bf16_t hh = (bf16_t)x; h0[i] = hh;
        float y = xs[i + 8]; bf16_t hy = (bf16_t)y; h1[i] = hy;
        if (SPLIT) { l0[i] = (bf16_t)(x - (float)hh); l1[i] = (bf16_t)(y - (float)hy); }
    }
    *(bf16x8*)&hi[eoff]     = h0;
    *(bf16x8*)&hi[eoff + 8] = h1;
    if (SPLIT) { *(bf16x8*)&lo[eoff] = l0; *(bf16x8*)&lo[eoff + 8] = l1; }
}

// Unified MFMA GEMM: C[m][n] = sum_k A[m][k] * B'[n][k]   (all operands NT, k-contig)
// M_SPLIT3: A,B f32, reg-staged hi/lo, 3 MFMA passes (drops lo*lo)
// M_PLAIN : A f32 -> bf16 (hi only), B bf16 via global_load_lds
// M_CONCAT: A = k<K1 ? f32 Af : bf16 A2b; B bf16 via global_load_lds
template<int MODE, bool BIAS, bool RELU, bool OUTBF16>
__global__ __launch_bounds__(256) void mgemm(
    const float* __restrict__ Af, const bf16_t* __restrict__ A2b,
    const float* __restrict__ Bf, const bf16_t* __restrict__ Bb,
    const float* __restrict__ bias,
    float* __restrict__ Cf, bf16_t* __restrict__ Cb,
    int K, int K1,
    long aB, long a2B, long bB, long cB,
    int lda, int lda2, int ldb, int ldc)
{
    constexpr int NS = (MODE == M_SPLIT3) ? 2 : 1;
    __shared__ bf16_t As[NS][BM * BKK];
    __shared__ bf16_t Bs[NS][BM * BKK];

    const int tid = threadIdx.x;
    const long z = blockIdx.z;
    const int m0 = blockIdx.y * BM, n0 = blockIdx.x * BN;

    const int sr = tid >> 1, sc = (tid & 1) * 16;   // f32 reg-stage map
    const int gr = tid >> 2, gc = (tid & 3) * 8;    // gload_lds map
    const int wlds = (tid >> 6) * 512;              // per-wave LDS elem base

    const int l = tid & 63;
    const int wv = tid >> 6;
    const int wr = (wv >> 1) * 64, wc = (wv & 1) * 64;
    const int fr = l & 15, fq = l >> 4;

    f32x4 acc[4][4] = {};

    for (int k0 = 0; k0 < K; k0 += BKK) {
        // ---- stage A ----
        if (MODE != M_CONCAT || k0 < K1) {
            const float* s = Af + z * aB + (long)(m0 + sr) * lda + k0 + sc;
            stage_tile_f32<MODE == M_SPLIT3>(s, As[0], As[NS - 1], sr * BKK + sc);
        } else {
            const bf16_t* s = A2b + z * a2B + (long)(m0 + gr) * lda2 + (k0 - K1) + gc;
            gload16(s, &As[0][wlds]);
            gload16(s + (long)64 * lda2, &As[0][2048 + wlds]);
        }
        // ---- stage B ----
        if (MODE == M_SPLIT3) {
            const float* s = Bf + z * bB + (long)(n0 + sr) * ldb + k0 + sc;
            stage_tile_f32<true>(s, Bs[0], Bs[NS - 1], sr * BKK + sc);
        } else {
            const bf16_t* s = Bb + z * bB + (long)(n0 + gr) * ldb + k0 + gc;
            gload16(s, &Bs[0][wlds]);
            gload16(s + (long)64 * ldb, &Bs[0][2048 + wlds]);
        }
        __syncthreads();

        // ---- fragments + MFMA ----
        bf16x8 a_h[4], b_h[4], a_l[4], b_l[4];
        #pragma unroll
        for (int i = 0; i < 4; i++) {
            a_h[i] = *(const bf16x8*)&As[0][(wr + i * 16 + fr) * BKK + fq * 8];
            b_h[i] = *(const bf16x8*)&Bs[0][(wc + i * 16 + fr) * BKK + fq * 8];
            if (MODE == M_SPLIT3) {
                a_l[i] = *(const bf16x8*)&As[NS - 1][(wr + i * 16 + fr) * BKK + fq * 8];
                b_l[i] = *(const bf16x8*)&Bs[NS - 1][(wc + i * 16 + fr) * BKK + fq * 8];
            }
        }
        #pragma unroll
        for (int mi = 0; mi < 4; mi++)
            #pragma unroll
            for (int ni = 0; ni < 4; ni++) {
                acc[mi][ni] = __builtin_amdgcn_mfma_f32_16x16x32_bf16(a_h[mi], b_h[ni], acc[mi][ni], 0, 0, 0);
                if (MODE == M_SPLIT3) {
                    acc[mi][ni] = __builtin_amdgcn_mfma_f32_16x16x32_bf16(a_h[mi], b_l[ni], acc[mi][ni], 0, 0, 0);
                    acc[mi][ni] = __builtin_amdgcn_mfma_f32_16x16x32_bf16(a_l[mi], b_h[ni], acc[mi][ni], 0, 0, 0);
                }
            }
        __syncthreads();
    }

    // ---- epilogue ----
    #pragma unroll
    for (int ni = 0; ni < 4; ni++) {
        const int col = n0 + wc + ni * 16 + fr;
        const float bv = BIAS ? bias[col] : 0.f;
        #pragma unroll
        for (int mi = 0; mi < 4; mi++) {
            #pragma unroll
            for (int j = 0; j < 4; j++) {
                const int row = m0 + wr + mi * 16 + fq * 4 + j;
                float v = acc[mi][ni][j] + bv;
                if (RELU) v = fmaxf(v, 0.f);
                if (OUTBF16) Cb[z * cB + (long)row * ldc + col] = (bf16_t)v;
                else         Cf[z * cB + (long)row * ldc + col] = v;
            }
        }
    }
}

// out[c][r] = (OutT) in[r][c]; grid (C/32, R/32, Z), block 256
template<typename OutT>
__global__ __launch_bounds__(256) void transpose_cvt(
    const float* __restrict__ in, OutT* __restrict__ out,
    int R, int C, long inB, long outB)
{
    __shared__ float tile[32][33];
    const long z = blockIdx.z;
    const float* src = in + z * inB;
    OutT* dst = out + z * outB;
    const int x0 = blockIdx.x * 32, y0 = blockIdx.y * 32;
    const int tx = threadIdx.x & 31, ty = threadIdx.x >> 5;
    #pragma unroll
    for (int i = 0; i < 32; i += 8)
        tile[ty + i][tx] = src[(long)(y0 + ty + i) * C + x0 + tx];
    __syncthreads();
    #pragma unroll
    for (int i = 0; i < 32; i += 8)
        dst[(long)(x0 + ty + i) * R + y0 + tx] = (OutT)tile[tx][ty + i];
}

// Row-wise masked softmax over sim rows. Matches AllenNLP legacy semantics.
__global__ __launch_bounds__(384) void masked_softmax_row(
    const float* __restrict__ S, const int* __restrict__ mask,
    float* __restrict__ out)
{
    const int row = blockIdx.x;        // b*384 + p
    const int b = row / 384;
    const int t = threadIdx.x;         // h
    __shared__ float redmax[6], redsum[6];

    float v = S[(long)row * 384 + t];
    int mm = mask[b * 384 + t];

    float x = mm ? v : -3.4e38f;
    #pragma unroll
    for (int o = 32; o > 0; o >>= 1) x = fmaxf(x, __shfl_xor(x, o, 64));
    int wid = t >> 6, lane = t & 63;
    if (lane == 0) redmax[wid] = x;
    __syncthreads();
    float mx = redmax[0];
    #pragma unroll
    for (int w = 1; w < 6; w++) mx = fmaxf(mx, redmax[w]);

    float e = mm ? expf(v - mx) : 0.f;
    float s = e;
    #pragma unroll
    for (int o = 32; o > 0; o >>= 1) s += __shfl_xor(s, o, 64);
    if (lane == 0) redsum[wid] = s;
    __syncthreads();
    float tot = 0.f;
    #pragma unroll
    for (int w = 0; w < 6; w++) tot += redsum[w];

    out[(long)row * 384 + t] = (tot > 0.f) ? e / tot : 0.f;
}

// Column-wise masked softmax: h2p[b][h][p] = softmax_p(sim[b][p][h] ; pm)
__global__ __launch_bounds__(384) void masked_softmax_col(
    const float* __restrict__ S, const int* __restrict__ mask,
    float* __restrict__ out)
{
    const int row = blockIdx.x;        // b*384 + h
    const int b = row / 384;
    const int h = row - b * 384;
    const int t = threadIdx.x;         // p
    __shared__ float redmax[6], redsum[6];

    float v = S[(long)b * SIM_B + (long)t * 384 + h];
    int mm = mask[b * 384 + t];

    float x = mm ? v : -3.4e38f;
    #pragma unroll
    for (int o = 32; o > 0; o >>= 1) x = fmaxf(x, __shfl_xor(x, o, 64));
    int wid = t >> 6, lane = t & 63;
    if (lane == 0) redmax[wid] = x;
    __syncthreads();
    float mx = redmax[0];
    #pragma unroll
    for (int w = 1; w < 6; w++) mx = fmaxf(mx, redmax[w]);

    float e = mm ? expf(v - mx) : 0.f;
    float s = e;
    #pragma unroll
    for (int o = 32; o > 0; o >>= 1) s += __shfl_xor(s, o, 64);
    if (lane == 0) redsum[wid] = s;
    __syncthreads();
    float tot = 0.f;
    #pragma unroll
    for (int w = 0; w < 6; w++) tot += redsum[w];

    out[(long)row * 384 + t] = (tot > 0.f) ? e / tot : 0.f;
}

// compared[b][off+d] = sum_p cmp[b][p][d] * mask[b][p]
__global__ __launch_bounds__(128) void masked_sum_kernel(
    const float* __restrict__ cmp, const int* __restrict__ mask,
    float* __restrict__ G, int off)
{
    const int b = blockIdx.y;
    const int d = blockIdx.x * 128 + threadIdx.x;
    float acc = 0.f;
    const float* base = cmp + (long)b * EMB_B + d;
    const int* mrow = mask + b * 384;
    for (int p = 0; p < 384; p++)
        acc += base[(long)p * 512] * (float)mrow[p];
    G[(long)b * 1024 + off + d] = acc;
}

__global__ __launch_bounds__(256) void final_kernel(
    const float* __restrict__ G, const float* __restrict__ W1,
    const float* __restrict__ b1, const float* __restrict__ W2,
    const float* __restrict__ b2, float* __restrict__ out)
{
    const int b = blockIdx.x;
    const int t = threadIdx.x;
    __shared__ float g[1024];
    __shared__ float h[512];
    const float* grow = G + (long)b * 1024;
    for (int i = t; i < 1024; i += 256) g[i] = grow[i];
    __syncthreads();
    for (int j = t; j < 512; j += 256) {
        float acc = b1[j];
        for (int k = 0; k < 1024; k++) acc = fmaf(g[k], W1[(long)k * 512 + j], acc);
        h[j] = fmaxf(acc, 0.f);
    }
    __syncthreads();
    if (t == 0) {
        float lg[3];
        #pragma unroll
        for (int c = 0; c < 3; c++) {
            float acc = b2[c];
            for (int j = 0; j < 512; j++) acc = fmaf(h[j], W2[j * 3 + c], acc);
            lg[c] = acc;
        }
        float mx = fmaxf(lg[0], fmaxf(lg[1], lg[2]));
        float e0 = expf(lg[0] - mx), e1 = expf(lg[1] - mx), e2 = expf(lg[2] - mx);
        float s = e0 + e1 + e2;
        out[OUT_LOGITS + b * 3 + 0] = lg[0];
        out[OUT_LOGITS + b * 3 + 1] = lg[1];
        out[OUT_LOGITS + b * 3 + 2] = lg[2];
        out[OUT_PROBS + b * 3 + 0] = e0 / s;
        out[OUT_PROBS + b * 3 + 1] = e1 / s;
        out[OUT_PROBS + b * 3 + 2] = e2 / s;
    }
}

extern "C" void kernel_launch(void* const* d_in, const int* in_sizes, int n_in,
                              void* d_out, int out_size, void* d_ws, size_t ws_size,
                              hipStream_t stream) {
    const float* emb_p = (const float*)d_in[0];
    const float* emb_h = (const float*)d_in[1];
    const int* pm = (const int*)d_in[2];
    const int* hm = (const int*)d_in[3];
    const float* Wa = (const float*)d_in[4];
    const float* ba = (const float*)d_in[5];
    const float* Wc = (const float*)d_in[6];
    const float* bc = (const float*)d_in[7];
    const float* W1 = (const float*)d_in[8];
    const float* b1 = (const float*)d_in[9];
    const float* W2 = (const float*)d_in[10];
    const float* b2 = (const float*)d_in[11];
    float* out = (float*)d_out;
    char* W = (char*)d_ws;

    float*  WaT   = (float*)(W + OFF_WAT);            // [512a][512d] f32
    bf16_t* WcT   = (bf16_t*)(W + OFF_WCT);           // [512n][1024k] bf16
    float*  projp = (float*)(W + OFF_P1);             // [12288][512] f32
    float*  projh = (float*)(W + OFF_P2);             // [12288][512] f32
    float*  sim   = (float*)(W + OFF_SIM);            // [32][384][384] f32
    float*  G     = (float*)(W + OFF_G);              // [32][1024] f32
    // aliases (lifetime-disjoint)
    bf16_t* atth  = (bf16_t*)(W + OFF_P1);                       // [12288][512] bf16
    bf16_t* attp  = (bf16_t*)(W + OFF_P1 + 12582912L);           // [12288][512] bf16
    bf16_t* embTp = (bf16_t*)(W + OFF_P2);                       // [32][512][384] bf16
    bf16_t* embTh = (bf16_t*)(W + OFF_P2 + 12582912L);           // [32][512][384] bf16
    float*  cmp   = (float*)(W + OFF_P2);                        // [12288][512] f32

    // 0: weight transposes
    transpose_cvt<float><<<dim3(16, 16, 1), 256, 0, stream>>>(Wa, WaT, 512, 512, 0, 0);
    transpose_cvt<bf16_t><<<dim3(16, 32, 1), 256, 0, stream>>>(Wc, WcT, 1024, 512, 0, 0);

    // 1,2: proj = relu(emb @ Wa + ba), split-bf16 3-pass
    mgemm<M_SPLIT3, true, true, false><<<dim3(4, 96, 1), 256, 0, stream>>>(
        emb_p, nullptr, WaT, nullptr, ba, projp, nullptr,
        512, 0, 0, 0, 0, 0, 512, 0, 512, 512);
    mgemm<M_SPLIT3, true, true, false><<<dim3(4, 96, 1), 256, 0, stream>>>(
        emb_h, nullptr, WaT, nullptr, ba, projh, nullptr,
        512, 0, 0, 0, 0, 0, 512, 0, 512, 512);

    // 3: sim[b,p,h] = proj_p . proj_h (batched NT), split-bf16 3-pass
    mgemm<M_SPLIT3, false, false, false><<<dim3(3, 3, 32), 256, 0, stream>>>(
        projp, nullptr, projh, nullptr, nullptr, sim, nullptr,
        512, 0, EMB_B, 0, EMB_B, SIM_B, 512, 0, 512, 384);

    // 4,5: masked softmaxes -> d_out (f32 exact path)
    masked_softmax_row<<<NPH, 384, 0, stream>>>(sim, hm, out + OUT_P2H);
    masked_softmax_col<<<NPH, 384, 0, stream>>>(sim, pm, out + OUT_H2P);

    // 6: emb transposes -> bf16 (per batch [384][512] -> [512][384])
    transpose_cvt<bf16_t><<<dim3(16, 12, 32), 256, 0, stream>>>(emb_p, embTp, 384, 512, EMB_B, EMB_B);
    transpose_cvt<bf16_t><<<dim3(16, 12, 32), 256, 0, stream>>>(emb_h, embTh, 384, 512, EMB_B, EMB_B);

    // 7,8: attention apply (plain bf16), outputs bf16
    mgemm<M_PLAIN, false, false, true><<<dim3(4, 3, 32), 256, 0, stream>>>(
        out + OUT_P2H, nullptr, nullptr, embTh, nullptr, nullptr, atth,
        384, 0, SIM_B, 0, (long)512 * 384, EMB_B, 384, 0, 384, 512);
    mgemm<M_PLAIN, false, false, true><<<dim3(4, 3, 32), 256, 0, stream>>>(
        out + OUT_H2P, nullptr, nullptr, embTp, nullptr, nullptr, attp,
        384, 0, SIM_B, 0, (long)512 * 384, EMB_B, 384, 0, 384, 512);

    // 9,10: cmp_p = relu(concat(emb_p, att_h) @ Wc + bc); masked sum
    mgemm<M_CONCAT, true, true, false><<<dim3(4, 96, 1), 256, 0, stream>>>(
        emb_p, atth, nullptr, WcT, bc, cmp, nullptr,
        1024, 512, 0, 0, 0, 0, 512, 512, 1024, 512);
    masked_sum_kernel<<<dim3(4, 32), 128, 0, stream>>>(cmp, pm, G, 0);

    // 11,12: cmp_h
    mgemm<M_CONCAT, true, true, false><<<dim3(4, 96, 1), 256, 0, stream>>>(
        emb_h, attp, nullptr, WcT, bc, cmp, nullptr,
        1024, 512, 0, 0, 0, 0, 512, 512, 1024, 512);
    masked_sum_kernel<<<dim3(4, 32), 128, 0, stream>>>(cmp, hm, G, 512);

    // 13: aggregate MLP + softmax
    final_kernel<<<32, 256, 0, stream>>>(G, W1, b1, W2, b2, out);
}

// Round 5
// 476.637 us; speedup vs baseline: 2.0912x; 1.0852x over previous
//
#include <hip/hip_runtime.h>
#include <hip/hip_bf16.h>
#include <math.h>

typedef __bf16 bf16_t;
typedef __bf16 bf16x8 __attribute__((ext_vector_type(8)));
typedef float f32x4 __attribute__((ext_vector_type(4)));

// Problem dims
#define NPH 12288          // B*P = B*H
#define SIM_B (384*384)
#define EMB_B (384*512)

// d_out offsets (floats)
#define OUT_LOGITS 0
#define OUT_PROBS 96
#define OUT_H2P 192
#define OUT_P2H (192 + 32*384*384)

// ws offsets (bytes)
#define OFF_WAT 0L
#define OFF_WCT 1048576L
#define OFF_P1  2097152L
#define OFF_P2  (OFF_P1 + 25165824L)
#define OFF_SIM (OFF_P2 + 25165824L)
#define OFF_G   (OFF_SIM + 18874368L)
#define OFF_H   (OFF_G + 131072L)
#define OFF_CM  (OFF_H + 65536L)
#define OFF_CS  (OFF_CM + 49152L)

#define BM 128
#define BN 128
#define BKK 32

#define M_SPLIT3 0
#define M_PLAIN  1
#define M_CONCAT 2

__device__ inline void gload16(const void* g, void* l) {
    __builtin_amdgcn_global_load_lds(
        (const __attribute__((address_space(1))) void*)g,
        (__attribute__((address_space(3))) void*)l, 16, 0, 0);
}

// Stage 16 consecutive f32 -> bf16 hi (and optionally lo) into LDS
template<bool SPLIT>
__device__ inline void stage_tile_f32(const float* __restrict__ s,
                                      bf16_t* hi, bf16_t* lo, int eoff)
{
    float xs[16];
    *(float4*)&xs[0]  = *(const float4*)(s);
    *(float4*)&xs[4]  = *(const float4*)(s + 4);
    *(float4*)&xs[8]  = *(const float4*)(s + 8);
    *(float4*)&xs[12] = *(const float4*)(s + 12);
    bf16x8 h0, h1, l0, l1;
    #pragma unroll
    for (int i = 0; i < 8; i++) {
        float x = xs[i];     bf16_t hh = (bf16_t)x; h0[i] = hh;
        float y = xs[i + 8]; bf16_t hy = (bf16_t)y; h1[i] = hy;
        if (SPLIT) { l0[i] = (bf16_t)(x - (float)hh); l1[i] = (bf16_t)(y - (float)hy); }
    }
    *(bf16x8*)&hi[eoff]     = h0;
    *(bf16x8*)&hi[eoff + 8] = h1;
    if (SPLIT) { *(bf16x8*)&lo[eoff] = l0; *(bf16x8*)&lo[eoff + 8] = l1; }
}

// Unified MFMA GEMM: C[m][n] = sum_k A[m][k] * B'[n][k]   (all operands NT, k-contig)
template<int MODE, bool BIAS, bool RELU, bool OUTBF16>
__global__ __launch_bounds__(256) void mgemm(
    const float* __restrict__ Af, const bf16_t* __restrict__ A2b,
    const float* __restrict__ Bf, const bf16_t* __restrict__ Bb,
    const float* __restrict__ bias,
    float* __restrict__ Cf, bf16_t* __restrict__ Cb,
    int K, int K1,
    long aB, long a2B, long bB, long cB,
    int lda, int lda2, int ldb, int ldc)
{
    constexpr int NS = (MODE == M_SPLIT3) ? 2 : 1;
    __shared__ bf16_t As[NS][BM * BKK];
    __shared__ bf16_t Bs[NS][BM * BKK];

    const int tid = threadIdx.x;
    const long z = blockIdx.z;
    const int m0 = blockIdx.y * BM, n0 = blockIdx.x * BN;

    const int sr = tid >> 1, sc = (tid & 1) * 16;   // f32 reg-stage map
    const int gr = tid >> 2, gc = (tid & 3) * 8;    // gload_lds map
    const int wlds = (tid >> 6) * 512;              // per-wave LDS elem base

    const int l = tid & 63;
    const int wv = tid >> 6;
    const int wr = (wv >> 1) * 64, wc = (wv & 1) * 64;
    const int fr = l & 15, fq = l >> 4;

    f32x4 acc[4][4] = {};

    for (int k0 = 0; k0 < K; k0 += BKK) {
        // ---- stage A ----
        if (MODE != M_CONCAT || k0 < K1) {
            const float* s = Af + z * aB + (long)(m0 + sr) * lda + k0 + sc;
            stage_tile_f32<MODE == M_SPLIT3>(s, As[0], As[NS - 1], sr * BKK + sc);
        } else {
            const bf16_t* s = A2b + z * a2B + (long)(m0 + gr) * lda2 + (k0 - K1) + gc;
            gload16(s, &As[0][wlds]);
            gload16(s + (long)64 * lda2, &As[0][2048 + wlds]);
        }
        // ---- stage B ----
        if (MODE == M_SPLIT3) {
            const float* s = Bf + z * bB + (long)(n0 + sr) * ldb + k0 + sc;
            stage_tile_f32<true>(s, Bs[0], Bs[NS - 1], sr * BKK + sc);
        } else {
            const bf16_t* s = Bb + z * bB + (long)(n0 + gr) * ldb + k0 + gc;
            gload16(s, &Bs[0][wlds]);
            gload16(s + (long)64 * ldb, &Bs[0][2048 + wlds]);
        }
        __syncthreads();

        // ---- fragments + MFMA ----
        bf16x8 a_h[4], b_h[4], a_l[4], b_l[4];
        #pragma unroll
        for (int i = 0; i < 4; i++) {
            a_h[i] = *(const bf16x8*)&As[0][(wr + i * 16 + fr) * BKK + fq * 8];
            b_h[i] = *(const bf16x8*)&Bs[0][(wc + i * 16 + fr) * BKK + fq * 8];
            if (MODE == M_SPLIT3) {
                a_l[i] = *(const bf16x8*)&As[NS - 1][(wr + i * 16 + fr) * BKK + fq * 8];
                b_l[i] = *(const bf16x8*)&Bs[NS - 1][(wc + i * 16 + fr) * BKK + fq * 8];
            }
        }
        #pragma unroll
        for (int mi = 0; mi < 4; mi++)
            #pragma unroll
            for (int ni = 0; ni < 4; ni++) {
                acc[mi][ni] = __builtin_amdgcn_mfma_f32_16x16x32_bf16(a_h[mi], b_h[ni], acc[mi][ni], 0, 0, 0);
                if (MODE == M_SPLIT3) {
                    acc[mi][ni] = __builtin_amdgcn_mfma_f32_16x16x32_bf16(a_h[mi], b_l[ni], acc[mi][ni], 0, 0, 0);
                    acc[mi][ni] = __builtin_amdgcn_mfma_f32_16x16x32_bf16(a_l[mi], b_h[ni], acc[mi][ni], 0, 0, 0);
                }
            }
        __syncthreads();
    }

    // ---- epilogue ----
    #pragma unroll
    for (int ni = 0; ni < 4; ni++) {
        const int col = n0 + wc + ni * 16 + fr;
        const float bv = BIAS ? bias[col] : 0.f;
        #pragma unroll
        for (int mi = 0; mi < 4; mi++) {
            #pragma unroll
            for (int j = 0; j < 4; j++) {
                const int row = m0 + wr + mi * 16 + fq * 4 + j;
                float v = acc[mi][ni][j] + bv;
                if (RELU) v = fmaxf(v, 0.f);
                if (OUTBF16) Cb[z * cB + (long)row * ldc + col] = (bf16_t)v;
                else         Cf[z * cB + (long)row * ldc + col] = v;
            }
        }
    }
}

// out[c][r] = (OutT) in[r][c]; grid (C/32, R/32, Z), block 256
template<typename OutT>
__global__ __launch_bounds__(256) void transpose_cvt(
    const float* __restrict__ in, OutT* __restrict__ out,
    int R, int C, long inB, long outB)
{
    __shared__ float tile[32][33];
    const long z = blockIdx.z;
    const float* src = in + z * inB;
    OutT* dst = out + z * outB;
    const int x0 = blockIdx.x * 32, y0 = blockIdx.y * 32;
    const int tx = threadIdx.x & 31, ty = threadIdx.x >> 5;
    #pragma unroll
    for (int i = 0; i < 32; i += 8)
        tile[ty + i][tx] = src[(long)(y0 + ty + i) * C + x0 + tx];
    __syncthreads();
    #pragma unroll
    for (int i = 0; i < 32; i += 8)
        dst[(long)(x0 + ty + i) * R + y0 + tx] = (OutT)tile[tx][ty + i];
}

// Row-wise masked softmax over sim rows (AllenNLP legacy semantics).
__global__ __launch_bounds__(384) void masked_softmax_row(
    const float* __restrict__ S, const int* __restrict__ mask,
    float* __restrict__ out)
{
    const int row = blockIdx.x;        // b*384 + p
    const int b = row / 384;
    const int t = threadIdx.x;         // h
    __shared__ float redmax[6], redsum[6];

    float v = S[(long)row * 384 + t];
    int mm = mask[b * 384 + t];

    float x = mm ? v : -3.4e38f;
    #pragma unroll
    for (int o = 32; o > 0; o >>= 1) x = fmaxf(x, __shfl_xor(x, o, 64));
    int wid = t >> 6, lane = t & 63;
    if (lane == 0) redmax[wid] = x;
    __syncthreads();
    float mx = redmax[0];
    #pragma unroll
    for (int w = 1; w < 6; w++) mx = fmaxf(mx, redmax[w]);

    float e = mm ? expf(v - mx) : 0.f;
    float s = e;
    #pragma unroll
    for (int o = 32; o > 0; o >>= 1) s += __shfl_xor(s, o, 64);
    if (lane == 0) redsum[wid] = s;
    __syncthreads();
    float tot = 0.f;
    #pragma unroll
    for (int w = 0; w < 6; w++) tot += redsum[w];

    out[(long)row * 384 + t] = (tot > 0.f) ? e / tot : 0.f;
}

// ---- Column softmax, pass 1: online max/sum over p (masked), coalesced ----
// grid (3 hc, 32 b), block 256. Thread: parity pp = t>>7, h = h0 + (t&127).
__global__ __launch_bounds__(256) void col_stats(
    const float* __restrict__ S, const int* __restrict__ mask,
    float* __restrict__ cmax, float* __restrict__ csum)
{
    __shared__ int pml[384];
    __shared__ float mred[2][128], sred[2][128];
    const int b = blockIdx.y;
    const int h0 = blockIdx.x * 128;
    const int t = threadIdx.x;
    const int pp = t >> 7, hh = t & 127;

    for (int i = t; i < 384; i += 256) pml[i] = mask[b * 384 + i];
    __syncthreads();

    const float* Sb = S + (long)b * SIM_B + h0 + hh;
    float m = -3.4e38f, s = 0.f;
    for (int p = pp; p < 384; p += 2) {
        if (pml[p]) {                    // wave-uniform branch
            float v = Sb[(long)p * 384];
            float nm = fmaxf(m, v);
            s = s * expf(m - nm) + expf(v - nm);
            m = nm;
        }
    }
    mred[pp][hh] = m; sred[pp][hh] = s;
    __syncthreads();
    if (t < 128) {
        float m0 = mred[0][t], m1 = mred[1][t];
        float s0 = sred[0][t], s1 = sred[1][t];
        float M = fmaxf(m0, m1);
        float e0 = (s0 > 0.f) ? s0 * expf(m0 - M) : 0.f;
        float e1 = (s1 > 0.f) ? s1 * expf(m1 - M) : 0.f;
        cmax[b * 384 + h0 + t] = M;
        csum[b * 384 + h0 + t] = e0 + e1;
    }
}

// ---- Column softmax, pass 2: fused transpose + normalize ----
// grid (12 htile, 12 ptile, 32 b), block 256. out[b][h][p].
__global__ __launch_bounds__(256) void col_write(
    const float* __restrict__ S, const int* __restrict__ mask,
    const float* __restrict__ cmax, const float* __restrict__ csum,
    float* __restrict__ out)
{
    __shared__ float tile[32][33];
    const int b = blockIdx.z;
    const int h0 = blockIdx.x * 32, p0 = blockIdx.y * 32;
    const int tx = threadIdx.x & 31, ty = threadIdx.x >> 5;
    const float* src = S + (long)b * SIM_B;
    #pragma unroll
    for (int i = 0; i < 32; i += 8)
        tile[ty + i][tx] = src[(long)(p0 + ty + i) * 384 + h0 + tx];  // rows=p, cols=h
    __syncthreads();
    const int pm_v = mask[b * 384 + p0 + tx];
    float* dst = out + (long)b * SIM_B;
    #pragma unroll
    for (int i = 0; i < 32; i += 8) {
        const int h = h0 + ty + i;
        const float mx = cmax[b * 384 + h];
        const float tot = csum[b * 384 + h];
        float v = tile[tx][ty + i];
        float r = (pm_v && tot > 0.f) ? expf(v - mx) / tot : 0.f;
        dst[(long)h * 384 + p0 + tx] = r;
    }
}

// compared[b][off+d] = sum_p cmp[b][p][d] * mask[b][p]
__global__ __launch_bounds__(128) void masked_sum_kernel(
    const float* __restrict__ cmp, const int* __restrict__ mask,
    float* __restrict__ G, int off)
{
    const int b = blockIdx.y;
    const int d = blockIdx.x * 128 + threadIdx.x;
    float acc = 0.f;
    const float* base = cmp + (long)b * EMB_B + d;
    const int* mrow = mask + b * 384;
    for (int p = 0; p < 384; p++)
        acc += base[(long)p * 512] * (float)mrow[p];
    G[(long)b * 1024 + off + d] = acc;
}

// hidden = relu(G @ W1 + b1), parallel: grid (8 jc, 32 b), block 256 (4-way k-split)
__global__ __launch_bounds__(256) void hidden_kernel(
    const float* __restrict__ G, const float* __restrict__ W1,
    const float* __restrict__ b1, float* __restrict__ Hbuf)
{
    __shared__ float g[1024];
    __shared__ float part[4][64];
    const int b = blockIdx.y, j0 = blockIdx.x * 64;
    const int t = threadIdx.x;
    const float* grow = G + (long)b * 1024;
    for (int i = t; i < 1024; i += 256) g[i] = grow[i];
    __syncthreads();
    const int tj = t & 63, tk = t >> 6;
    const float* w = W1 + (long)(tk * 256) * 512 + j0 + tj;
    const float* gk = g + tk * 256;
    float acc = 0.f;
    #pragma unroll 8
    for (int k = 0; k < 256; k++)
        acc = fmaf(gk[k], w[(long)k * 512], acc);
    part[tk][tj] = acc;
    __syncthreads();
    if (t < 64) {
        float v = part[0][t] + part[1][t] + part[2][t] + part[3][t] + b1[j0 + t];
        Hbuf[(long)b * 512 + j0 + t] = fmaxf(v, 0.f);
    }
}

// logits + probs: grid 32, block 64 (one wave per batch)
__global__ __launch_bounds__(64) void logits_kernel(
    const float* __restrict__ Hbuf, const float* __restrict__ W2,
    const float* __restrict__ b2, float* __restrict__ out)
{
    const int b = blockIdx.x, l = threadIdx.x;
    const float* h = Hbuf + (long)b * 512;
    float a0 = 0.f, a1 = 0.f, a2 = 0.f;
    #pragma unroll
    for (int k = l; k < 512; k += 64) {
        float hv = h[k];
        a0 = fmaf(hv, W2[k * 3 + 0], a0);
        a1 = fmaf(hv, W2[k * 3 + 1], a1);
        a2 = fmaf(hv, W2[k * 3 + 2], a2);
    }
    #pragma unroll
    for (int o = 32; o > 0; o >>= 1) {
        a0 += __shfl_xor(a0, o, 64);
        a1 += __shfl_xor(a1, o, 64);
        a2 += __shfl_xor(a2, o, 64);
    }
    if (l == 0) {
        float l0 = a0 + b2[0], l1 = a1 + b2[1], l2 = a2 + b2[2];
        float mx = fmaxf(l0, fmaxf(l1, l2));
        float e0 = expf(l0 - mx), e1 = expf(l1 - mx), e2 = expf(l2 - mx);
        float s = e0 + e1 + e2;
        out[OUT_LOGITS + b * 3 + 0] = l0;
        out[OUT_LOGITS + b * 3 + 1] = l1;
        out[OUT_LOGITS + b * 3 + 2] = l2;
        out[OUT_PROBS + b * 3 + 0] = e0 / s;
        out[OUT_PROBS + b * 3 + 1] = e1 / s;
        out[OUT_PROBS + b * 3 + 2] = e2 / s;
    }
}

extern "C" void kernel_launch(void* const* d_in, const int* in_sizes, int n_in,
                              void* d_out, int out_size, void* d_ws, size_t ws_size,
                              hipStream_t stream) {
    const float* emb_p = (const float*)d_in[0];
    const float* emb_h = (const float*)d_in[1];
    const int* pm = (const int*)d_in[2];
    const int* hm = (const int*)d_in[3];
    const float* Wa = (const float*)d_in[4];
    const float* ba = (const float*)d_in[5];
    const float* Wc = (const float*)d_in[6];
    const float* bc = (const float*)d_in[7];
    const float* W1 = (const float*)d_in[8];
    const float* b1 = (const float*)d_in[9];
    const float* W2 = (const float*)d_in[10];
    const float* b2 = (const float*)d_in[11];
    float* out = (float*)d_out;
    char* W = (char*)d_ws;

    float*  WaT   = (float*)(W + OFF_WAT);            // [512a][512d] f32
    bf16_t* WcT   = (bf16_t*)(W + OFF_WCT);           // [512n][1024k] bf16
    float*  projp = (float*)(W + OFF_P1);             // [12288][512] f32
    float*  projh = (float*)(W + OFF_P2);             // [12288][512] f32
    float*  sim   = (float*)(W + OFF_SIM);            // [32][384][384] f32
    float*  G     = (float*)(W + OFF_G);              // [32][1024] f32
    float*  Hbuf  = (float*)(W + OFF_H);              // [32][512] f32
    float*  cmaxb = (float*)(W + OFF_CM);             // [32][384] f32
    float*  csumb = (float*)(W + OFF_CS);             // [32][384] f32
    // aliases (lifetime-disjoint)
    bf16_t* atth  = (bf16_t*)(W + OFF_P1);                       // [12288][512] bf16
    bf16_t* attp  = (bf16_t*)(W + OFF_P1 + 12582912L);           // [12288][512] bf16
    bf16_t* embTp = (bf16_t*)(W + OFF_P2);                       // [32][512][384] bf16
    bf16_t* embTh = (bf16_t*)(W + OFF_P2 + 12582912L);           // [32][512][384] bf16
    float*  cmp   = (float*)(W + OFF_P2);                        // [12288][512] f32

    // 0: weight transposes
    transpose_cvt<float><<<dim3(16, 16, 1), 256, 0, stream>>>(Wa, WaT, 512, 512, 0, 0);
    transpose_cvt<bf16_t><<<dim3(16, 32, 1), 256, 0, stream>>>(Wc, WcT, 1024, 512, 0, 0);

    // 1,2: proj = relu(emb @ Wa + ba), split-bf16 3-pass
    mgemm<M_SPLIT3, true, true, false><<<dim3(4, 96, 1), 256, 0, stream>>>(
        emb_p, nullptr, WaT, nullptr, ba, projp, nullptr,
        512, 0, 0, 0, 0, 0, 512, 0, 512, 512);
    mgemm<M_SPLIT3, true, true, false><<<dim3(4, 96, 1), 256, 0, stream>>>(
        emb_h, nullptr, WaT, nullptr, ba, projh, nullptr,
        512, 0, 0, 0, 0, 0, 512, 0, 512, 512);

    // 3: sim[b,p,h] = proj_p . proj_h (batched NT), split-bf16 3-pass
    mgemm<M_SPLIT3, false, false, false><<<dim3(3, 3, 32), 256, 0, stream>>>(
        projp, nullptr, projh, nullptr, nullptr, sim, nullptr,
        512, 0, EMB_B, 0, EMB_B, SIM_B, 512, 0, 512, 384);

    // 4: p2h row softmax -> d_out (f32 exact path)
    masked_softmax_row<<<NPH, 384, 0, stream>>>(sim, hm, out + OUT_P2H);
    // 5: h2p column softmax: stats + fused-transpose write
    col_stats<<<dim3(3, 32), 256, 0, stream>>>(sim, pm, cmaxb, csumb);
    col_write<<<dim3(12, 12, 32), 256, 0, stream>>>(sim, pm, cmaxb, csumb, out + OUT_H2P);

    // 6: emb transposes -> bf16 (per batch [384][512] -> [512][384])
    transpose_cvt<bf16_t><<<dim3(16, 12, 32), 256, 0, stream>>>(emb_p, embTp, 384, 512, EMB_B, EMB_B);
    transpose_cvt<bf16_t><<<dim3(16, 12, 32), 256, 0, stream>>>(emb_h, embTh, 384, 512, EMB_B, EMB_B);

    // 7,8: attention apply (plain bf16), outputs bf16
    mgemm<M_PLAIN, false, false, true><<<dim3(4, 3, 32), 256, 0, stream>>>(
        out + OUT_P2H, nullptr, nullptr, embTh, nullptr, nullptr, atth,
        384, 0, SIM_B, 0, (long)512 * 384, EMB_B, 384, 0, 384, 512);
    mgemm<M_PLAIN, false, false, true><<<dim3(4, 3, 32), 256, 0, stream>>>(
        out + OUT_H2P, nullptr, nullptr, embTp, nullptr, nullptr, attp,
        384, 0, SIM_B, 0, (long)512 * 384, EMB_B, 384, 0, 384, 512);

    // 9,10: cmp_p = relu(concat(emb_p, att_h) @ Wc + bc); masked sum
    mgemm<M_CONCAT, true, true, false><<<dim3(4, 96, 1), 256, 0, stream>>>(
        emb_p, atth, nullptr, WcT, bc, cmp, nullptr,
        1024, 512, 0, 0, 0, 0, 512, 512, 1024, 512);
    masked_sum_kernel<<<dim3(4, 32), 128, 0, stream>>>(cmp, pm, G, 0);

    // 11,12: cmp_h
    mgemm<M_CONCAT, true, true, false><<<dim3(4, 96, 1), 256, 0, stream>>>(
        emb_h, attp, nullptr, WcT, bc, cmp, nullptr,
        1024, 512, 0, 0, 0, 0, 512, 512, 1024, 512);
    masked_sum_kernel<<<dim3(4, 32), 128, 0, stream>>>(cmp, hm, G, 512);

    // 13: aggregate MLP + softmax (parallelized)
    hidden_kernel<<<dim3(8, 32), 256, 0, stream>>>(G, W1, b1, Hbuf);
    logits_kernel<<<32, 64, 0, stream>>>(Hbuf, W2, b2, out);
}

// Round 6
// 452.236 us; speedup vs baseline: 2.2041x; 1.0540x over previous
//
#include <hip/hip_runtime.h>
#include <hip/hip_bf16.h>
#include <math.h>

typedef __bf16 bf16_t;
typedef __bf16 bf16x8 __attribute__((ext_vector_type(8)));
typedef float f32x4 __attribute__((ext_vector_type(4)));

// Problem dims
#define NPH 12288          // B*P = B*H
#define SIM_B (384*384)
#define EMB_B (384*512)

// d_out offsets (floats)
#define OUT_LOGITS 0
#define OUT_PROBS 96
#define OUT_H2P 192
#define OUT_P2H (192 + 32*384*384)

// ws offsets (bytes)
#define OFF_WAT 0L
#define OFF_WCT 1048576L
#define OFF_P1  2097152L
#define OFF_P2  (OFF_P1 + 25165824L)
#define OFF_SIM (OFF_P2 + 25165824L)
#define OFF_H   (OFF_SIM + 18874368L)
#define OFF_CM  (OFF_H + 65536L)
#define OFF_CS  (OFF_CM + 49152L)
#define OFF_GP  (OFF_CS + 49152L)

#define BM 128
#define BN 128
#define BKK 32

#define M_SPLIT3 0
#define M_PLAIN  1
#define M_CONCAT 2

__device__ inline void gload16(const void* g, void* l) {
    __builtin_amdgcn_global_load_lds(
        (const __attribute__((address_space(1))) void*)g,
        (__attribute__((address_space(3))) void*)l, 16, 0, 0);
}

// Stage 16 consecutive f32 -> bf16 hi (and optionally lo) into LDS
template<bool SPLIT>
__device__ inline void stage_tile_f32(const float* __restrict__ s,
                                      bf16_t* hi, bf16_t* lo, int eoff)
{
    float xs[16];
    *(float4*)&xs[0]  = *(const float4*)(s);
    *(float4*)&xs[4]  = *(const float4*)(s + 4);
    *(float4*)&xs[8]  = *(const float4*)(s + 8);
    *(float4*)&xs[12] = *(const float4*)(s + 12);
    bf16x8 h0, h1, l0, l1;
    #pragma unroll
    for (int i = 0; i < 8; i++) {
        float x = xs[i];     bf16_t hh = (bf16_t)x; h0[i] = hh;
        float y = xs[i + 8]; bf16_t hy = (bf16_t)y; h1[i] = hy;
        if (SPLIT) { l0[i] = (bf16_t)(x - (float)hh); l1[i] = (bf16_t)(y - (float)hy); }
    }
    *(bf16x8*)&hi[eoff]     = h0;
    *(bf16x8*)&hi[eoff + 8] = h1;
    if (SPLIT) { *(bf16x8*)&lo[eoff] = l0; *(bf16x8*)&lo[eoff + 8] = l1; }
}

// Unified MFMA GEMM: C[m][n] = sum_k A[m][k] * B'[n][k]   (all operands NT, k-contig)
template<int MODE, bool BIAS, bool RELU, bool OUTBF16>
__global__ __launch_bounds__(256) void mgemm(
    const float* __restrict__ Af, const bf16_t* __restrict__ A2b,
    const float* __restrict__ Bf, const bf16_t* __restrict__ Bb,
    const float* __restrict__ bias,
    float* __restrict__ Cf, bf16_t* __restrict__ Cb,
    int K, int K1,
    long aB, long a2B, long bB, long cB,
    int lda, int lda2, int ldb, int ldc)
{
    constexpr int NS = (MODE == M_SPLIT3) ? 2 : 1;
    __shared__ bf16_t As[NS][BM * BKK];
    __shared__ bf16_t Bs[NS][BM * BKK];

    const int tid = threadIdx.x;
    const long z = blockIdx.z;
    const int m0 = blockIdx.y * BM, n0 = blockIdx.x * BN;

    const int sr = tid >> 1, sc = (tid & 1) * 16;   // f32 reg-stage map
    const int gr = tid >> 2, gc = (tid & 3) * 8;    // gload_lds map
    const int wlds = (tid >> 6) * 512;              // per-wave LDS elem base

    const int l = tid & 63;
    const int wv = tid >> 6;
    const int wr = (wv >> 1) * 64, wc = (wv & 1) * 64;
    const int fr = l & 15, fq = l >> 4;

    f32x4 acc[4][4] = {};

    for (int k0 = 0; k0 < K; k0 += BKK) {
        // ---- stage A ----
        if (MODE != M_CONCAT || k0 < K1) {
            const float* s = Af + z * aB + (long)(m0 + sr) * lda + k0 + sc;
            stage_tile_f32<MODE == M_SPLIT3>(s, As[0], As[NS - 1], sr * BKK + sc);
        } else {
            const bf16_t* s = A2b + z * a2B + (long)(m0 + gr) * lda2 + (k0 - K1) + gc;
            gload16(s, &As[0][wlds]);
            gload16(s + (long)64 * lda2, &As[0][2048 + wlds]);
        }
        // ---- stage B ----
        if (MODE == M_SPLIT3) {
            const float* s = Bf + z * bB + (long)(n0 + sr) * ldb + k0 + sc;
            stage_tile_f32<true>(s, Bs[0], Bs[NS - 1], sr * BKK + sc);
        } else {
            const bf16_t* s = Bb + z * bB + (long)(n0 + gr) * ldb + k0 + gc;
            gload16(s, &Bs[0][wlds]);
            gload16(s + (long)64 * ldb, &Bs[0][2048 + wlds]);
        }
        __syncthreads();

        // ---- fragments + MFMA ----
        bf16x8 a_h[4], b_h[4], a_l[4], b_l[4];
        #pragma unroll
        for (int i = 0; i < 4; i++) {
            a_h[i] = *(const bf16x8*)&As[0][(wr + i * 16 + fr) * BKK + fq * 8];
            b_h[i] = *(const bf16x8*)&Bs[0][(wc + i * 16 + fr) * BKK + fq * 8];
            if (MODE == M_SPLIT3) {
                a_l[i] = *(const bf16x8*)&As[NS - 1][(wr + i * 16 + fr) * BKK + fq * 8];
                b_l[i] = *(const bf16x8*)&Bs[NS - 1][(wc + i * 16 + fr) * BKK + fq * 8];
            }
        }
        #pragma unroll
        for (int mi = 0; mi < 4; mi++)
            #pragma unroll
            for (int ni = 0; ni < 4; ni++) {
                acc[mi][ni] = __builtin_amdgcn_mfma_f32_16x16x32_bf16(a_h[mi], b_h[ni], acc[mi][ni], 0, 0, 0);
                if (MODE == M_SPLIT3) {
                    acc[mi][ni] = __builtin_amdgcn_mfma_f32_16x16x32_bf16(a_h[mi], b_l[ni], acc[mi][ni], 0, 0, 0);
                    acc[mi][ni] = __builtin_amdgcn_mfma_f32_16x16x32_bf16(a_l[mi], b_h[ni], acc[mi][ni], 0, 0, 0);
                }
            }
        __syncthreads();
    }

    // ---- epilogue ----
    #pragma unroll
    for (int ni = 0; ni < 4; ni++) {
        const int col = n0 + wc + ni * 16 + fr;
        const float bv = BIAS ? bias[col] : 0.f;
        #pragma unroll
        for (int mi = 0; mi < 4; mi++) {
            #pragma unroll
            for (int j = 0; j < 4; j++) {
                const int row = m0 + wr + mi * 16 + fq * 4 + j;
                float v = acc[mi][ni][j] + bv;
                if (RELU) v = fmaxf(v, 0.f);
                if (OUTBF16) Cb[z * cB + (long)row * ldc + col] = (bf16_t)v;
                else         Cf[z * cB + (long)row * ldc + col] = v;
            }
        }
    }
}

// out[c][r] = (OutT) in[r][c]; grid (C/32, R/32, Z), block 256
template<typename OutT>
__global__ __launch_bounds__(256) void transpose_cvt(
    const float* __restrict__ in, OutT* __restrict__ out,
    int R, int C, long inB, long outB)
{
    __shared__ float tile[32][33];
    const long z = blockIdx.z;
    const float* src = in + z * inB;
    OutT* dst = out + z * outB;
    const int x0 = blockIdx.x * 32, y0 = blockIdx.y * 32;
    const int tx = threadIdx.x & 31, ty = threadIdx.x >> 5;
    #pragma unroll
    for (int i = 0; i < 32; i += 8)
        tile[ty + i][tx] = src[(long)(y0 + ty + i) * C + x0 + tx];
    __syncthreads();
    #pragma unroll
    for (int i = 0; i < 32; i += 8)
        dst[(long)(x0 + ty + i) * R + y0 + tx] = (OutT)tile[tx][ty + i];
}

// Row-wise masked softmax over sim rows (AllenNLP legacy semantics).
__global__ __launch_bounds__(384) void masked_softmax_row(
    const float* __restrict__ S, const int* __restrict__ mask,
    float* __restrict__ out)
{
    const int row = blockIdx.x;        // b*384 + p
    const int b = row / 384;
    const int t = threadIdx.x;         // h
    __shared__ float redmax[6], redsum[6];

    float v = S[(long)row * 384 + t];
    int mm = mask[b * 384 + t];

    float x = mm ? v : -3.4e38f;
    #pragma unroll
    for (int o = 32; o > 0; o >>= 1) x = fmaxf(x, __shfl_xor(x, o, 64));
    int wid = t >> 6, lane = t & 63;
    if (lane == 0) redmax[wid] = x;
    __syncthreads();
    float mx = redmax[0];
    #pragma unroll
    for (int w = 1; w < 6; w++) mx = fmaxf(mx, redmax[w]);

    float e = mm ? expf(v - mx) : 0.f;
    float s = e;
    #pragma unroll
    for (int o = 32; o > 0; o >>= 1) s += __shfl_xor(s, o, 64);
    if (lane == 0) redsum[wid] = s;
    __syncthreads();
    float tot = 0.f;
    #pragma unroll
    for (int w = 0; w < 6; w++) tot += redsum[w];

    out[(long)row * 384 + t] = (tot > 0.f) ? e / tot : 0.f;
}

// ---- Column softmax, pass 1: max-then-sum (no serial transcendental chain) ----
// grid (6 hc, 32 b), block 256: tk = t>>6 (4 p-groups), hh = t&63.
__global__ __launch_bounds__(256) void col_stats(
    const float* __restrict__ S, const int* __restrict__ mask,
    float* __restrict__ cmax, float* __restrict__ csum)
{
    __shared__ int pml[384];
    __shared__ float mred[4][64], sred[4][64];
    const int b = blockIdx.y;
    const int h0 = blockIdx.x * 64;
    const int t = threadIdx.x;
    const int tk = t >> 6, hh = t & 63;

    for (int i = t; i < 384; i += 256) pml[i] = mask[b * 384 + i];
    __syncthreads();

    const float* Sb = S + (long)b * SIM_B + h0 + hh;
    // pass 1: masked max (independent loads, cheap fmax chain)
    float m = -3.4e38f;
    for (int p = tk; p < 384; p += 4)
        if (pml[p]) m = fmaxf(m, Sb[(long)p * 384]);   // wave-uniform branch
    mred[tk][hh] = m;
    __syncthreads();
    const float M = fmaxf(fmaxf(mred[0][hh], mred[1][hh]),
                          fmaxf(mred[2][hh], mred[3][hh]));
    // pass 2: sum of exp (L2-hot re-read; exps independent)
    float s = 0.f;
    for (int p = tk; p < 384; p += 4)
        if (pml[p]) s += expf(Sb[(long)p * 384] - M);
    sred[tk][hh] = s;
    __syncthreads();
    if (t < 64) {
        const float Mf = fmaxf(fmaxf(mred[0][t], mred[1][t]),
                               fmaxf(mred[2][t], mred[3][t]));
        cmax[b * 384 + h0 + t] = Mf;
        csum[b * 384 + h0 + t] = sred[0][t] + sred[1][t] + sred[2][t] + sred[3][t];
    }
}

// ---- Column softmax, pass 2: fused transpose + normalize ----
// grid (12 htile, 12 ptile, 32 b), block 256. out[b][h][p].
__global__ __launch_bounds__(256) void col_write(
    const float* __restrict__ S, const int* __restrict__ mask,
    const float* __restrict__ cmax, const float* __restrict__ csum,
    float* __restrict__ out)
{
    __shared__ float tile[32][33];
    const int b = blockIdx.z;
    const int h0 = blockIdx.x * 32, p0 = blockIdx.y * 32;
    const int tx = threadIdx.x & 31, ty = threadIdx.x >> 5;
    const float* src = S + (long)b * SIM_B;
    #pragma unroll
    for (int i = 0; i < 32; i += 8)
        tile[ty + i][tx] = src[(long)(p0 + ty + i) * 384 + h0 + tx];  // rows=p, cols=h
    __syncthreads();
    const int pm_v = mask[b * 384 + p0 + tx];
    float* dst = out + (long)b * SIM_B;
    #pragma unroll
    for (int i = 0; i < 32; i += 8) {
        const int h = h0 + ty + i;
        const float mx = cmax[b * 384 + h];
        const float tot = csum[b * 384 + h];
        float v = tile[tx][ty + i];
        float r = (pm_v && tot > 0.f) ? expf(v - mx) / tot : 0.f;
        dst[(long)h * 384 + p0 + tx] = r;
    }
}

// partial compared sums: Gp[pc][b][off+d] = sum_{p in chunk pc} cmp[b][p][d]*mask[b][p]
// grid (4 d-chunks, 4 p-chunks, 32 b), block 128
__global__ __launch_bounds__(128) void masked_sum_kernel(
    const float* __restrict__ cmp, const int* __restrict__ mask,
    float* __restrict__ Gp, int off)
{
    const int b = blockIdx.z, pc = blockIdx.y;
    const int d = blockIdx.x * 128 + threadIdx.x;
    float acc = 0.f;
    const float* base = cmp + (long)b * EMB_B + d;
    const int* mrow = mask + b * 384;
    const int p0 = pc * 96;
    for (int p = p0; p < p0 + 96; p++)
        acc += base[(long)p * 512] * (float)mrow[p];
    Gp[((long)pc * 32 + b) * 1024 + off + d] = acc;
}

// hidden = relu(G @ W1 + b1); combines 4 p-chunk partials while loading G.
// grid (8 jc, 32 b), block 256 (4-way k-split)
__global__ __launch_bounds__(256) void hidden_kernel(
    const float* __restrict__ Gp, const float* __restrict__ W1,
    const float* __restrict__ b1, float* __restrict__ Hbuf)
{
    __shared__ float g[1024];
    __shared__ float part[4][64];
    const int b = blockIdx.y, j0 = blockIdx.x * 64;
    const int t = threadIdx.x;
    for (int i = t; i < 1024; i += 256)
        g[i] = Gp[((long)0 * 32 + b) * 1024 + i] + Gp[((long)1 * 32 + b) * 1024 + i]
             + Gp[((long)2 * 32 + b) * 1024 + i] + Gp[((long)3 * 32 + b) * 1024 + i];
    __syncthreads();
    const int tj = t & 63, tk = t >> 6;
    const float* w = W1 + (long)(tk * 256) * 512 + j0 + tj;
    const float* gk = g + tk * 256;
    float acc = 0.f;
    #pragma unroll 8
    for (int k = 0; k < 256; k++)
        acc = fmaf(gk[k], w[(long)k * 512], acc);
    part[tk][tj] = acc;
    __syncthreads();
    if (t < 64) {
        float v = part[0][t] + part[1][t] + part[2][t] + part[3][t] + b1[j0 + t];
        Hbuf[(long)b * 512 + j0 + t] = fmaxf(v, 0.f);
    }
}

// logits + probs: grid 32, block 64 (one wave per batch)
__global__ __launch_bounds__(64) void logits_kernel(
    const float* __restrict__ Hbuf, const float* __restrict__ W2,
    const float* __restrict__ b2, float* __restrict__ out)
{
    const int b = blockIdx.x, l = threadIdx.x;
    const float* h = Hbuf + (long)b * 512;
    float a0 = 0.f, a1 = 0.f, a2 = 0.f;
    #pragma unroll
    for (int k = l; k < 512; k += 64) {
        float hv = h[k];
        a0 = fmaf(hv, W2[k * 3 + 0], a0);
        a1 = fmaf(hv, W2[k * 3 + 1], a1);
        a2 = fmaf(hv, W2[k * 3 + 2], a2);
    }
    #pragma unroll
    for (int o = 32; o > 0; o >>= 1) {
        a0 += __shfl_xor(a0, o, 64);
        a1 += __shfl_xor(a1, o, 64);
        a2 += __shfl_xor(a2, o, 64);
    }
    if (l == 0) {
        float l0 = a0 + b2[0], l1 = a1 + b2[1], l2 = a2 + b2[2];
        float mx = fmaxf(l0, fmaxf(l1, l2));
        float e0 = expf(l0 - mx), e1 = expf(l1 - mx), e2 = expf(l2 - mx);
        float s = e0 + e1 + e2;
        out[OUT_LOGITS + b * 3 + 0] = l0;
        out[OUT_LOGITS + b * 3 + 1] = l1;
        out[OUT_LOGITS + b * 3 + 2] = l2;
        out[OUT_PROBS + b * 3 + 0] = e0 / s;
        out[OUT_PROBS + b * 3 + 1] = e1 / s;
        out[OUT_PROBS + b * 3 + 2] = e2 / s;
    }
}

extern "C" void kernel_launch(void* const* d_in, const int* in_sizes, int n_in,
                              void* d_out, int out_size, void* d_ws, size_t ws_size,
                              hipStream_t stream) {
    const float* emb_p = (const float*)d_in[0];
    const float* emb_h = (const float*)d_in[1];
    const int* pm = (const int*)d_in[2];
    const int* hm = (const int*)d_in[3];
    const float* Wa = (const float*)d_in[4];
    const float* ba = (const float*)d_in[5];
    const float* Wc = (const float*)d_in[6];
    const float* bc = (const float*)d_in[7];
    const float* W1 = (const float*)d_in[8];
    const float* b1 = (const float*)d_in[9];
    const float* W2 = (const float*)d_in[10];
    const float* b2 = (const float*)d_in[11];
    float* out = (float*)d_out;
    char* W = (char*)d_ws;

    float*  WaT   = (float*)(W + OFF_WAT);            // [512a][512d] f32
    bf16_t* WcT   = (bf16_t*)(W + OFF_WCT);           // [512n][1024k] bf16
    float*  projp = (float*)(W + OFF_P1);             // [12288][512] f32
    float*  projh = (float*)(W + OFF_P2);             // [12288][512] f32
    float*  sim   = (float*)(W + OFF_SIM);            // [32][384][384] f32
    float*  Hbuf  = (float*)(W + OFF_H);              // [32][512] f32
    float*  cmaxb = (float*)(W + OFF_CM);             // [32][384] f32
    float*  csumb = (float*)(W + OFF_CS);             // [32][384] f32
    float*  Gp    = (float*)(W + OFF_GP);             // [4][32][1024] f32
    // aliases (lifetime-disjoint)
    bf16_t* atth  = (bf16_t*)(W + OFF_P1);                       // [12288][512] bf16
    bf16_t* attp  = (bf16_t*)(W + OFF_P1 + 12582912L);           // [12288][512] bf16
    bf16_t* embTp = (bf16_t*)(W + OFF_P2);                       // [32][512][384] bf16
    bf16_t* embTh = (bf16_t*)(W + OFF_P2 + 12582912L);           // [32][512][384] bf16
    float*  cmp   = (float*)(W + OFF_P2);                        // [12288][512] f32

    // 0: weight transposes
    transpose_cvt<float><<<dim3(16, 16, 1), 256, 0, stream>>>(Wa, WaT, 512, 512, 0, 0);
    transpose_cvt<bf16_t><<<dim3(16, 32, 1), 256, 0, stream>>>(Wc, WcT, 1024, 512, 0, 0);

    // 1,2: proj = relu(emb @ Wa + ba), split-bf16 3-pass
    mgemm<M_SPLIT3, true, true, false><<<dim3(4, 96, 1), 256, 0, stream>>>(
        emb_p, nullptr, WaT, nullptr, ba, projp, nullptr,
        512, 0, 0, 0, 0, 0, 512, 0, 512, 512);
    mgemm<M_SPLIT3, true, true, false><<<dim3(4, 96, 1), 256, 0, stream>>>(
        emb_h, nullptr, WaT, nullptr, ba, projh, nullptr,
        512, 0, 0, 0, 0, 0, 512, 0, 512, 512);

    // 3: sim[b,p,h] = proj_p . proj_h (batched NT), split-bf16 3-pass
    mgemm<M_SPLIT3, false, false, false><<<dim3(3, 3, 32), 256, 0, stream>>>(
        projp, nullptr, projh, nullptr, nullptr, sim, nullptr,
        512, 0, EMB_B, 0, EMB_B, SIM_B, 512, 0, 512, 384);

    // 4: p2h row softmax -> d_out (f32 exact path)
    masked_softmax_row<<<NPH, 384, 0, stream>>>(sim, hm, out + OUT_P2H);
    // 5: h2p column softmax: stats (max-then-sum) + fused-transpose write
    col_stats<<<dim3(6, 32), 256, 0, stream>>>(sim, pm, cmaxb, csumb);
    col_write<<<dim3(12, 12, 32), 256, 0, stream>>>(sim, pm, cmaxb, csumb, out + OUT_H2P);

    // 6: emb transposes -> bf16 (per batch [384][512] -> [512][384])
    transpose_cvt<bf16_t><<<dim3(16, 12, 32), 256, 0, stream>>>(emb_p, embTp, 384, 512, EMB_B, EMB_B);
    transpose_cvt<bf16_t><<<dim3(16, 12, 32), 256, 0, stream>>>(emb_h, embTh, 384, 512, EMB_B, EMB_B);

    // 7,8: attention apply (plain bf16), outputs bf16
    mgemm<M_PLAIN, false, false, true><<<dim3(4, 3, 32), 256, 0, stream>>>(
        out + OUT_P2H, nullptr, nullptr, embTh, nullptr, nullptr, atth,
        384, 0, SIM_B, 0, (long)512 * 384, EMB_B, 384, 0, 384, 512);
    mgemm<M_PLAIN, false, false, true><<<dim3(4, 3, 32), 256, 0, stream>>>(
        out + OUT_H2P, nullptr, nullptr, embTp, nullptr, nullptr, attp,
        384, 0, SIM_B, 0, (long)512 * 384, EMB_B, 384, 0, 384, 512);

    // 9,10: cmp_p = relu(concat(emb_p, att_h) @ Wc + bc); partial masked sums
    mgemm<M_CONCAT, true, true, false><<<dim3(4, 96, 1), 256, 0, stream>>>(
        emb_p, atth, nullptr, WcT, bc, cmp, nullptr,
        1024, 512, 0, 0, 0, 0, 512, 512, 1024, 512);
    masked_sum_kernel<<<dim3(4, 4, 32), 128, 0, stream>>>(cmp, pm, Gp, 0);

    // 11,12: cmp_h
    mgemm<M_CONCAT, true, true, false><<<dim3(4, 96, 1), 256, 0, stream>>>(
        emb_h, attp, nullptr, WcT, bc, cmp, nullptr,
        1024, 512, 0, 0, 0, 0, 512, 512, 1024, 512);
    masked_sum_kernel<<<dim3(4, 4, 32), 128, 0, stream>>>(cmp, hm, Gp, 512);

    // 13: aggregate MLP + softmax (partial-combining)
    hidden_kernel<<<dim3(8, 32), 256, 0, stream>>>(Gp, W1, b1, Hbuf);
    logits_kernel<<<32, 64, 0, stream>>>(Hbuf, W2, b2, out);
}

// Round 10
// 407.255 us; speedup vs baseline: 2.4475x; 1.1104x over previous
//
#include <hip/hip_runtime.h>
#include <hip/hip_bf16.h>
#include <math.h>

typedef __bf16 bf16_t;
typedef __bf16 bf16x8 __attribute__((ext_vector_type(8)));
typedef float f32x4 __attribute__((ext_vector_type(4)));

// Problem dims
#define NPH 12288          // B*P = B*H
#define SIM_B (384*384)
#define EMB_B (384*512)

// d_out offsets (floats)
#define OUT_LOGITS 0
#define OUT_PROBS 96
#define OUT_H2P 192
#define OUT_P2H (192 + 32*384*384)

// ws offsets (bytes)
#define OFF_WATH 0L
#define OFF_WATL 524288L
#define OFF_WCT  1048576L
#define OFF_A    2097152L          // 50 MB region, 4 x 6291456 bf16 elems
#define OFF_SIM  52428800L         // 18.9 MB f32
#define OFF_CM   71303168L
#define OFF_CS   (OFF_CM + 49152L)
#define OFF_GP   (OFF_CS + 49152L)
#define OFF_H    (OFF_GP + 524288L)

// element offsets within region A (bf16 elems)
#define PROJ_LO   6291456L         // lo offset from hi (also batch-block size)
#define PROJ_Z    12582912L        // proj z-stride (p -> h)
#define ATT_ALL_E 12582912L        // att_all elem base in region A
#define CMP_Z     6291456L

#define BM 128
#define BN 128
#define BKK 32

#define M_PROJ   0   // A: f32 reg-stage split; B: bf16 hi/lo gload; 3-pass
#define M_SPLITB 1   // A,B: bf16 hi/lo gload; 3-pass
#define M_PLAIN  2   // A: f32 reg-stage hi; B: bf16 gload; 1-pass
#define M_CONCAT 3   // A: k<K1 f32 reg-stage hi else bf16 gload; B: bf16 gload
#define O_F32   0
#define O_BF16  1
#define O_SPLIT 2

__device__ inline void gload16(const void* g, void* l) {
    __builtin_amdgcn_global_load_lds(
        (const __attribute__((address_space(1))) void*)g,
        (__attribute__((address_space(3))) void*)l, 16, 0, 0);
}

// Swizzled reg-stage: 16 consecutive f32 -> bf16 hi (+lo) into LDS row `row`,
// chunks c0,c0+1 stored at chunk^((row>>1)&3)  [bank-conflict-free read layout]
template<bool SPLIT>
__device__ inline void stage_sw(const float* __restrict__ s,
                                bf16_t* hi, bf16_t* lo, int row, int c0)
{
    float xs[16];
    *(float4*)&xs[0]  = *(const float4*)(s);
    *(float4*)&xs[4]  = *(const float4*)(s + 4);
    *(float4*)&xs[8]  = *(const float4*)(s + 8);
    *(float4*)&xs[12] = *(const float4*)(s + 12);
    bf16x8 h0, h1, l0, l1;
    #pragma unroll
    for (int i = 0; i < 8; i++) {
        float x = xs[i];     bf16_t hh = (bf16_t)x; h0[i] = hh;
        float y = xs[i + 8]; bf16_t hy = (bf16_t)y; h1[i] = hy;
        if (SPLIT) { l0[i] = (bf16_t)(x - (float)hh); l1[i] = (bf16_t)(y - (float)hy); }
    }
    const int key = (row >> 1) & 3;
    const int cc0 = c0 ^ key, cc1 = cc0 ^ 1;
    *(bf16x8*)&hi[row * 32 + cc0 * 8] = h0;
    *(bf16x8*)&hi[row * 32 + cc1 * 8] = h1;
    if (SPLIT) {
        *(bf16x8*)&lo[row * 32 + cc0 * 8] = l0;
        *(bf16x8*)&lo[row * 32 + cc1 * 8] = l1;
    }
}

// Unified MFMA GEMM: C[m][n] = sum_k A[m][k] * B'[n][k]  (NT, k-contig)
template<int MODE, int OUTK, bool BIAS, bool RELU>
__global__ __launch_bounds__(256) void mgemm(
    const float* __restrict__ Af, const float* __restrict__ Af2, int zalt,
    const bf16_t* __restrict__ Abh, long loA,
    const bf16_t* __restrict__ A2b, long a2B,
    const bf16_t* __restrict__ Bbh, long loB,
    const float* __restrict__ bias,
    float* __restrict__ Cf, bf16_t* __restrict__ Cb, long loC,
    int K, int K1,
    long aB, long bB, long cB,
    int lda, int lda2, int ldb, int ldc)
{
    constexpr int NS = (MODE == M_PROJ || MODE == M_SPLITB) ? 2 : 1;
    __shared__ bf16_t As[NS][BM * BKK];
    __shared__ bf16_t Bs[NS][BM * BKK];

    const int tid = threadIdx.x;
    const long z = blockIdx.z;
    const int m0 = blockIdx.y * BM, n0 = blockIdx.x * BN;

    const float* Afs = (MODE == M_PROJ || MODE == M_PLAIN || MODE == M_CONCAT)
                       ? ((z >= zalt) ? Af2 : Af) : nullptr;

    // reg-stage map (f32): 128 rows x 32 k, 16 elems/thread
    const int sr = tid >> 1, sc = (tid & 1) * 16, c0 = (tid & 1) * 2;
    // gload map: rows gr, gr+64; source chunk pre-swizzled
    const int gr = tid >> 2;
    const int gco = ((tid & 3) ^ ((gr >> 1) & 3)) * 8;
    const int wlds = (tid >> 6) * 512;

    const int l = tid & 63;
    const int wv = tid >> 6;
    const int wr = (wv >> 1) * 64, wc = (wv & 1) * 64;
    const int fr = l & 15, fq = l >> 4;

    f32x4 acc[4][4] = {};

    for (int k0 = 0; k0 < K; k0 += BKK) {
        // ---- stage A ----
        if (MODE == M_PROJ || MODE == M_PLAIN) {
            const float* s = Afs + z * aB + (long)(m0 + sr) * lda + k0 + sc;
            stage_sw<MODE == M_PROJ>(s, As[0], As[NS - 1], sr, c0);
        } else if (MODE == M_CONCAT) {
            if (k0 < K1) {
                const float* s = Afs + z * aB + (long)(m0 + sr) * lda + k0 + sc;
                stage_sw<false>(s, As[0], nullptr, sr, c0);
            } else {
                const bf16_t* s = A2b + z * a2B + (long)(m0 + gr) * lda2 + (k0 - K1) + gco;
                gload16(s, &As[0][wlds]);
                gload16(s + (long)64 * lda2, &As[0][2048 + wlds]);
            }
        } else { // M_SPLITB
            const bf16_t* s = Abh + z * aB + (long)(m0 + gr) * lda + k0 + gco;
            gload16(s, &As[0][wlds]);
            gload16(s + (long)64 * lda, &As[0][2048 + wlds]);
            gload16(s + loA, &As[NS - 1][wlds]);
            gload16(s + loA + (long)64 * lda, &As[NS - 1][2048 + wlds]);
        }
        // ---- stage B (always bf16 gload) ----
        {
            const bf16_t* s = Bbh + z * bB + (long)(n0 + gr) * ldb + k0 + gco;
            gload16(s, &Bs[0][wlds]);
            gload16(s + (long)64 * ldb, &Bs[0][2048 + wlds]);
            if (NS == 2) {
                gload16(s + loB, &Bs[NS - 1][wlds]);
                gload16(s + loB + (long)64 * ldb, &Bs[NS - 1][2048 + wlds]);
            }
        }
        __syncthreads();

        // ---- fragments (swizzled reads) + MFMA ----
        bf16x8 a_h[4], b_h[4], a_l[4], b_l[4];
        #pragma unroll
        for (int i = 0; i < 4; i++) {
            const int ra = wr + i * 16 + fr;
            const int rb = wc + i * 16 + fr;
            const int ka = (fq ^ ((ra >> 1) & 3)) * 8;
            const int kb = (fq ^ ((rb >> 1) & 3)) * 8;
            a_h[i] = *(const bf16x8*)&As[0][ra * 32 + ka];
            b_h[i] = *(const bf16x8*)&Bs[0][rb * 32 + kb];
            if (NS == 2) {
                a_l[i] = *(const bf16x8*)&As[NS - 1][ra * 32 + ka];
                b_l[i] = *(const bf16x8*)&Bs[NS - 1][rb * 32 + kb];
            }
        }
        #pragma unroll
        for (int mi = 0; mi < 4; mi++)
            #pragma unroll
            for (int ni = 0; ni < 4; ni++) {
                acc[mi][ni] = __builtin_amdgcn_mfma_f32_16x16x32_bf16(a_h[mi], b_h[ni], acc[mi][ni], 0, 0, 0);
                if (NS == 2) {
                    acc[mi][ni] = __builtin_amdgcn_mfma_f32_16x16x32_bf16(a_h[mi], b_l[ni], acc[mi][ni], 0, 0, 0);
                    acc[mi][ni] = __builtin_amdgcn_mfma_f32_16x16x32_bf16(a_l[mi], b_h[ni], acc[mi][ni], 0, 0, 0);
                }
            }
        __syncthreads();
    }

    // ---- epilogue ----
    #pragma unroll
    for (int ni = 0; ni < 4; ni++) {
        const int col = n0 + wc + ni * 16 + fr;
        const float bv = BIAS ? bias[col] : 0.f;
        #pragma unroll
        for (int mi = 0; mi < 4; mi++) {
            #pragma unroll
            for (int j = 0; j < 4; j++) {
                const int row = m0 + wr + mi * 16 + fq * 4 + j;
                float v = acc[mi][ni][j] + bv;
                if (RELU) v = fmaxf(v, 0.f);
                const long idx = z * cB + (long)row * ldc + col;
                if (OUTK == O_F32) Cf[idx] = v;
                else if (OUTK == O_BF16) Cb[idx] = (bf16_t)v;
                else {
                    bf16_t h = (bf16_t)v;
                    Cb[idx] = h;
                    Cb[idx + loC] = (bf16_t)(v - (float)h);
                }
            }
        }
    }
}

// out[c][r] = bf16(in[r][c]) (+ optional lo split); z-select between in/in2
template<bool SPLIT>
__global__ __launch_bounds__(256) void transpose_kernel(
    const float* __restrict__ in, const float* __restrict__ in2, int zsplit,
    bf16_t* __restrict__ out, bf16_t* __restrict__ outLo,
    int R, int C, long inB, long outB)
{
    __shared__ float tile[32][33];
    const int z = blockIdx.z;
    const float* src = (z >= zsplit) ? (in2 + (long)(z - zsplit) * inB)
                                     : (in + (long)z * inB);
    const int x0 = blockIdx.x * 32, y0 = blockIdx.y * 32;
    const int tx = threadIdx.x & 31, ty = threadIdx.x >> 5;
    #pragma unroll
    for (int i = 0; i < 32; i += 8)
        tile[ty + i][tx] = src[(long)(y0 + ty + i) * C + x0 + tx];
    __syncthreads();
    bf16_t* dst = out + (long)z * outB;
    bf16_t* dstL = SPLIT ? (outLo + (long)z * outB) : nullptr;
    #pragma unroll
    for (int i = 0; i < 32; i += 8) {
        float v = tile[tx][ty + i];
        bf16_t h = (bf16_t)v;
        dst[(long)(x0 + ty + i) * R + y0 + tx] = h;
        if (SPLIT) dstL[(long)(x0 + ty + i) * R + y0 + tx] = (bf16_t)(v - (float)h);
    }
}

// Row-wise masked softmax over sim rows (AllenNLP legacy semantics).
__global__ __launch_bounds__(384) void masked_softmax_row(
    const float* __restrict__ S, const int* __restrict__ mask,
    float* __restrict__ out)
{
    const int row = blockIdx.x;        // b*384 + p
    const int b = row / 384;
    const int t = threadIdx.x;         // h
    __shared__ float redmax[6], redsum[6];

    float v = S[(long)row * 384 + t];
    int mm = mask[b * 384 + t];

    float x = mm ? v : -3.4e38f;
    #pragma unroll
    for (int o = 32; o > 0; o >>= 1) x = fmaxf(x, __shfl_xor(x, o, 64));
    int wid = t >> 6, lane = t & 63;
    if (lane == 0) redmax[wid] = x;
    __syncthreads();
    float mx = redmax[0];
    #pragma unroll
    for (int w = 1; w < 6; w++) mx = fmaxf(mx, redmax[w]);

    float e = mm ? expf(v - mx) : 0.f;
    float s = e;
    #pragma unroll
    for (int o = 32; o > 0; o >>= 1) s += __shfl_xor(s, o, 64);
    if (lane == 0) redsum[wid] = s;
    __syncthreads();
    float tot = 0.f;
    #pragma unroll
    for (int w = 0; w < 6; w++) tot += redsum[w];

    out[(long)row * 384 + t] = (tot > 0.f) ? e / tot : 0.f;
}

// Column softmax pass 1: max-then-sum. grid (6 hc, 32 b), block 256.
__global__ __launch_bounds__(256) void col_stats(
    const float* __restrict__ S, const int* __restrict__ mask,
    float* __restrict__ cmax, float* __restrict__ csum)
{
    __shared__ int pml[384];
    __shared__ float mred[4][64], sred[4][64];
    const int b = blockIdx.y;
    const int h0 = blockIdx.x * 64;
    const int t = threadIdx.x;
    const int tk = t >> 6, hh = t & 63;

    for (int i = t; i < 384; i += 256) pml[i] = mask[b * 384 + i];
    __syncthreads();

    const float* Sb = S + (long)b * SIM_B + h0 + hh;
    float m = -3.4e38f;
    for (int p = tk; p < 384; p += 4)
        if (pml[p]) m = fmaxf(m, Sb[(long)p * 384]);
    mred[tk][hh] = m;
    __syncthreads();
    const float M = fmaxf(fmaxf(mred[0][hh], mred[1][hh]),
                          fmaxf(mred[2][hh], mred[3][hh]));
    float s = 0.f;
    for (int p = tk; p < 384; p += 4)
        if (pml[p]) s += expf(Sb[(long)p * 384] - M);
    sred[tk][hh] = s;
    __syncthreads();
    if (t < 64) {
        const float Mf = fmaxf(fmaxf(mred[0][t], mred[1][t]),
                               fmaxf(mred[2][t], mred[3][t]));
        cmax[b * 384 + h0 + t] = Mf;
        csum[b * 384 + h0 + t] = sred[0][t] + sred[1][t] + sred[2][t] + sred[3][t];
    }
}

// Column softmax pass 2: fused transpose + normalize. out[b][h][p].
__global__ __launch_bounds__(256) void col_write(
    const float* __restrict__ S, const int* __restrict__ mask,
    const float* __restrict__ cmax, const float* __restrict__ csum,
    float* __restrict__ out)
{
    __shared__ float tile[32][33];
    const int b = blockIdx.z;
    const int h0 = blockIdx.x * 32, p0 = blockIdx.y * 32;
    const int tx = threadIdx.x & 31, ty = threadIdx.x >> 5;
    const float* src = S + (long)b * SIM_B;
    #pragma unroll
    for (int i = 0; i < 32; i += 8)
        tile[ty + i][tx] = src[(long)(p0 + ty + i) * 384 + h0 + tx];
    __syncthreads();
    const int pm_v = mask[b * 384 + p0 + tx];
    float* dst = out + (long)b * SIM_B;
    #pragma unroll
    for (int i = 0; i < 32; i += 8) {
        const int h = h0 + ty + i;
        const float mx = cmax[b * 384 + h];
        const float tot = csum[b * 384 + h];
        float v = tile[tx][ty + i];
        float r = (pm_v && tot > 0.f) ? expf(v - mx) / tot : 0.f;
        dst[(long)h * 384 + p0 + tx] = r;
    }
}

// partial compared sums from bf16 cmp_all. grid (4 dc, 8 = pc|half<<2, 32 b)
__global__ __launch_bounds__(128) void masked_sum_kernel(
    const bf16_t* __restrict__ cmpb, const int* __restrict__ pm,
    const int* __restrict__ hm, float* __restrict__ Gp)
{
    const int b = blockIdx.z;
    const int pc = blockIdx.y & 3, half = blockIdx.y >> 2;
    const int d = blockIdx.x * 128 + threadIdx.x;
    const int* mrow = (half ? hm : pm) + b * 384;
    const bf16_t* base = cmpb + (long)half * CMP_Z + (long)b * EMB_B + d;
    float acc = 0.f;
    const int p0 = pc * 96;
    for (int p = p0; p < p0 + 96; p++)
        acc += (float)base[(long)p * 512] * (float)mrow[p];
    Gp[((long)pc * 32 + b) * 1024 + half * 512 + d] = acc;
}

// hidden = relu(G @ W1 + b1), combining 4 p-chunk partials. grid (8 jc, 32 b)
__global__ __launch_bounds__(256) void hidden_kernel(
    const float* __restrict__ Gp, const float* __restrict__ W1,
    const float* __restrict__ b1, float* __restrict__ Hbuf)
{
    __shared__ float g[1024];
    __shared__ float part[4][64];
    const int b = blockIdx.y, j0 = blockIdx.x * 64;
    const int t = threadIdx.x;
    for (int i = t; i < 1024; i += 256)
        g[i] = Gp[((long)0 * 32 + b) * 1024 + i] + Gp[((long)1 * 32 + b) * 1024 + i]
             + Gp[((long)2 * 32 + b) * 1024 + i] + Gp[((long)3 * 32 + b) * 1024 + i];
    __syncthreads();
    const int tj = t & 63, tk = t >> 6;
    const float* w = W1 + (long)(tk * 256) * 512 + j0 + tj;
    const float* gk = g + tk * 256;
    float acc = 0.f;
    #pragma unroll 8
    for (int k = 0; k < 256; k++)
        acc = fmaf(gk[k], w[(long)k * 512], acc);
    part[tk][tj] = acc;
    __syncthreads();
    if (t < 64) {
        float v = part[0][t] + part[1][t] + part[2][t] + part[3][t] + b1[j0 + t];
        Hbuf[(long)b * 512 + j0 + t] = fmaxf(v, 0.f);
    }
}

// logits + probs: grid 32, block 64
__global__ __launch_bounds__(64) void logits_kernel(
    const float* __restrict__ Hbuf, const float* __restrict__ W2,
    const float* __restrict__ b2, float* __restrict__ out)
{
    const int b = blockIdx.x, l = threadIdx.x;
    const float* h = Hbuf + (long)b * 512;
    float a0 = 0.f, a1 = 0.f, a2 = 0.f;
    #pragma unroll
    for (int k = l; k < 512; k += 64) {
        float hv = h[k];
        a0 = fmaf(hv, W2[k * 3 + 0], a0);
        a1 = fmaf(hv, W2[k * 3 + 1], a1);
        a2 = fmaf(hv, W2[k * 3 + 2], a2);
    }
    #pragma unroll
    for (int o = 32; o > 0; o >>= 1) {
        a0 += __shfl_xor(a0, o, 64);
        a1 += __shfl_xor(a1, o, 64);
        a2 += __shfl_xor(a2, o, 64);
    }
    if (l == 0) {
        float l0 = a0 + b2[0], l1 = a1 + b2[1], l2 = a2 + b2[2];
        float mx = fmaxf(l0, fmaxf(l1, l2));
        float e0 = expf(l0 - mx), e1 = expf(l1 - mx), e2 = expf(l2 - mx);
        float s = e0 + e1 + e2;
        out[OUT_LOGITS + b * 3 + 0] = l0;
        out[OUT_LOGITS + b * 3 + 1] = l1;
        out[OUT_LOGITS + b * 3 + 2] = l2;
        out[OUT_PROBS + b * 3 + 0] = e0 / s;
        out[OUT_PROBS + b * 3 + 1] = e1 / s;
        out[OUT_PROBS + b * 3 + 2] = e2 / s;
    }
}

extern "C" void kernel_launch(void* const* d_in, const int* in_sizes, int n_in,
                              void* d_out, int out_size, void* d_ws, size_t ws_size,
                              hipStream_t stream) {
    const float* emb_p = (const float*)d_in[0];
    const float* emb_h = (const float*)d_in[1];
    const int* pm = (const int*)d_in[2];
    const int* hm = (const int*)d_in[3];
    const float* Wa = (const float*)d_in[4];
    const float* ba = (const float*)d_in[5];
    const float* Wc = (const float*)d_in[6];
    const float* bc = (const float*)d_in[7];
    const float* W1 = (const float*)d_in[8];
    const float* b1 = (const float*)d_in[9];
    const float* W2 = (const float*)d_in[10];
    const float* b2 = (const float*)d_in[11];
    float* out = (float*)d_out;
    char* W = (char*)d_ws;

    bf16_t* WaTh  = (bf16_t*)(W + OFF_WATH);   // [512a][512d] hi
    bf16_t* WaTl  = (bf16_t*)(W + OFF_WATL);   // lo
    bf16_t* WcT   = (bf16_t*)(W + OFF_WCT);    // [512n][1024k]
    bf16_t* A     = (bf16_t*)(W + OFF_A);      // 50 MB region
    float*  sim   = (float*)(W + OFF_SIM);
    float*  cmaxb = (float*)(W + OFF_CM);
    float*  csumb = (float*)(W + OFF_CS);
    float*  Gp    = (float*)(W + OFF_GP);
    float*  Hbuf  = (float*)(W + OFF_H);
    // region-A aliases (lifetime-disjoint)
    bf16_t* projs  = A;                        // [hi_p|lo_p|hi_h|lo_h] x 6291456
    bf16_t* embT   = A;                        // [64][512][384] (p batches 0-31, h 32-63)
    bf16_t* attAll = A + ATT_ALL_E;            // [64][384][512] (attp 0-31, atth 32-63)
    bf16_t* cmpAll = A;                        // [2][12288][512] bf16

    // 0: weight transposes (WaT split bf16, WcT bf16)
    transpose_kernel<true><<<dim3(16, 16, 1), 256, 0, stream>>>(
        Wa, nullptr, 999, WaTh, WaTl, 512, 512, 0, 0);
    transpose_kernel<false><<<dim3(16, 32, 1), 256, 0, stream>>>(
        Wc, nullptr, 999, WcT, nullptr, 1024, 512, 0, 0);

    // 1: proj merged (z=0 premise, z=1 hypothesis), split bf16 output
    mgemm<M_PROJ, O_SPLIT, true, true><<<dim3(4, 96, 2), 256, 0, stream>>>(
        emb_p, emb_h, 1, nullptr, 0, nullptr, 0, WaTh, 262144L, ba,
        nullptr, projs, PROJ_LO,
        512, 0, 0L, 0L, PROJ_Z, 512, 0, 512, 512);

    // 2: sim (batched NT, hi/lo 3-pass, all-gload staging)
    mgemm<M_SPLITB, O_F32, false, false><<<dim3(3, 3, 32), 256, 0, stream>>>(
        nullptr, nullptr, 999, projs, PROJ_LO, nullptr, 0,
        projs + PROJ_Z, PROJ_LO, nullptr,
        sim, nullptr, 0,
        512, 0, (long)EMB_B, (long)EMB_B, (long)SIM_B, 512, 0, 512, 384);

    // 3: p2h row softmax -> d_out
    masked_softmax_row<<<NPH, 384, 0, stream>>>(sim, hm, out + OUT_P2H);
    // 4: h2p column softmax (stats + fused transpose write)
    col_stats<<<dim3(6, 32), 256, 0, stream>>>(sim, pm, cmaxb, csumb);
    col_write<<<dim3(12, 12, 32), 256, 0, stream>>>(sim, pm, cmaxb, csumb, out + OUT_H2P);

    // 5: emb transposes merged -> embT (z<32: emb_p, z>=32: emb_h)
    transpose_kernel<false><<<dim3(16, 12, 64), 256, 0, stream>>>(
        emb_p, emb_h, 32, embT, nullptr, 384, 512, (long)EMB_B, (long)EMB_B);

    // 6: attention apply merged: z<32: attp = h2p@embTp ; z>=32: atth = p2h@embTh
    mgemm<M_PLAIN, O_BF16, false, false><<<dim3(4, 3, 64), 256, 0, stream>>>(
        out + OUT_H2P, nullptr, 1 << 30, nullptr, 0, nullptr, 0,
        embT, 0, nullptr,
        nullptr, attAll, 0,
        384, 0, (long)SIM_B, (long)EMB_B, (long)EMB_B, 384, 0, 384, 512);

    // 7: cmp merged: z=0: relu(cat(emb_p, atth)@Wc+bc); z=1: cat(emb_h, attp)
    mgemm<M_CONCAT, O_BF16, true, true><<<dim3(4, 96, 2), 256, 0, stream>>>(
        emb_p, emb_h, 1, nullptr, 0,
        attAll + CMP_Z, -(long)CMP_Z,       // z=0 -> atth, z=1 -> attp
        WcT, 0, bc,
        nullptr, cmpAll, 0,
        1024, 512, 0L, 0L, (long)CMP_Z, 512, 512, 1024, 512);

    // 8: masked partial sums (both halves)
    masked_sum_kernel<<<dim3(4, 8, 32), 128, 0, stream>>>(cmpAll, pm, hm, Gp);

    // 9: aggregate MLP + softmax
    hidden_kernel<<<dim3(8, 32), 256, 0, stream>>>(Gp, W1, b1, Hbuf);
    logits_kernel<<<32, 64, 0, stream>>>(Hbuf, W2, b2, out);
}

// Round 11
// 380.890 us; speedup vs baseline: 2.6169x; 1.0692x over previous
//
#include <hip/hip_runtime.h>
#include <hip/hip_bf16.h>
#include <math.h>

typedef __bf16 bf16_t;
typedef __bf16 bf16x8 __attribute__((ext_vector_type(8)));
typedef float f32x4 __attribute__((ext_vector_type(4)));

// Problem dims
#define NPH 12288          // B*P = B*H
#define SIM_B (384*384)
#define EMB_B (384*512)

// d_out offsets (floats)
#define OUT_LOGITS 0
#define OUT_PROBS 96
#define OUT_H2P 192
#define OUT_P2H (192 + 32*384*384)

// ws offsets (bytes)
#define OFF_WATH 0L
#define OFF_WATL 524288L
#define OFF_WCT  1048576L
#define OFF_A    2097152L          // 50 MB region, 4 x 6291456 bf16 elems
#define OFF_SIM  52428800L         // 18.9 MB f32
#define OFF_CM   71303168L
#define OFF_CS   (OFF_CM + 49152L)
#define OFF_GP   (OFF_CS + 49152L)
#define OFF_H    (OFF_GP + 524288L)

// element offsets within region A (bf16 elems)
#define PROJ_LO   6291456L         // lo offset from hi (also batch-block size)
#define PROJ_Z    12582912L        // proj z-stride (p -> h)
#define ATT_ALL_E 12582912L        // att_all elem base in region A
#define CMP_Z     6291456L

#define BM 128
#define BN 128
#define BKK 32

#define M_PROJ   0   // A: f32 reg-stage split; B: bf16 hi/lo gload; 3-pass
#define M_SPLITB 1   // A,B: bf16 hi/lo gload; 3-pass
#define M_PLAIN  2   // A: f32 reg-stage hi; B: bf16 gload; 1-pass
#define M_CONCAT 3   // A: k<K1 f32 reg-stage hi else bf16 gload; B: bf16 gload
#define O_F32   0
#define O_BF16  1
#define O_SPLIT 2
#define O_GSUM  3    // no C store; masked row-sum partials -> Gp (Cf)

__device__ inline void gload16(const void* g, void* l) {
    __builtin_amdgcn_global_load_lds(
        (const __attribute__((address_space(1))) void*)g,
        (__attribute__((address_space(3))) void*)l, 16, 0, 0);
}

// Swizzled reg-stage: 16 consecutive f32 -> bf16 hi (+lo) into LDS row `row`,
// chunks c0,c0+1 stored at chunk^((row>>1)&3)  [bank-conflict-free read layout]
template<bool SPLIT>
__device__ inline void stage_sw(const float* __restrict__ s,
                                bf16_t* hi, bf16_t* lo, int row, int c0)
{
    float xs[16];
    *(float4*)&xs[0]  = *(const float4*)(s);
    *(float4*)&xs[4]  = *(const float4*)(s + 4);
    *(float4*)&xs[8]  = *(const float4*)(s + 8);
    *(float4*)&xs[12] = *(const float4*)(s + 12);
    bf16x8 h0, h1, l0, l1;
    #pragma unroll
    for (int i = 0; i < 8; i++) {
        float x = xs[i];     bf16_t hh = (bf16_t)x; h0[i] = hh;
        float y = xs[i + 8]; bf16_t hy = (bf16_t)y; h1[i] = hy;
        if (SPLIT) { l0[i] = (bf16_t)(x - (float)hh); l1[i] = (bf16_t)(y - (float)hy); }
    }
    const int key = (row >> 1) & 3;
    const int cc0 = c0 ^ key, cc1 = cc0 ^ 1;
    *(bf16x8*)&hi[row * 32 + cc0 * 8] = h0;
    *(bf16x8*)&hi[row * 32 + cc1 * 8] = h1;
    if (SPLIT) {
        *(bf16x8*)&lo[row * 32 + cc0 * 8] = l0;
        *(bf16x8*)&lo[row * 32 + cc1 * 8] = l1;
    }
}

// Unified MFMA GEMM: C[m][n] = sum_k A[m][k] * B'[n][k]  (NT, k-contig)
// Block IDs are XCD-chunk swizzled: blocks sharing an A-panel land on one XCD.
template<int MODE, int OUTK, bool BIAS, bool RELU>
__global__ __launch_bounds__(256) void mgemm(
    const float* __restrict__ Af, const float* __restrict__ Af2, int zalt,
    const bf16_t* __restrict__ Abh, long loA,
    const bf16_t* __restrict__ A2b, long a2B,
    const bf16_t* __restrict__ Bbh, long loB,
    const float* __restrict__ bias,
    const int* __restrict__ pmask, const int* __restrict__ hmask,
    float* __restrict__ Cf, bf16_t* __restrict__ Cb, long loC,
    int K, int K1,
    long aB, long bB, long cB,
    int lda, int lda2, int ldb, int ldc)
{
    constexpr int NS = (MODE == M_PROJ || MODE == M_SPLITB) ? 2 : 1;
    __shared__ bf16_t As[NS][BM * BKK];
    __shared__ bf16_t Bs[NS][BM * BKK];

    const int tid = threadIdx.x;

    // ---- XCD-chunked block swizzle (bijective: all grids are %8 == 0) ----
    const int gx = gridDim.x, gy = gridDim.y;
    const int nwg = gx * gy * gridDim.z;
    int flat = blockIdx.x + gx * (blockIdx.y + gy * blockIdx.z);
    flat = (flat & 7) * (nwg >> 3) + (flat >> 3);
    const int bz_ = flat / (gx * gy);
    const int rem_ = flat - bz_ * (gx * gy);
    const int by_ = rem_ / gx, bx_ = rem_ - by_ * gx;

    const long z = bz_;
    const int m0 = by_ * BM, n0 = bx_ * BN;

    const float* Afs = (MODE == M_PROJ || MODE == M_PLAIN || MODE == M_CONCAT)
                       ? ((z >= zalt) ? Af2 : Af) : nullptr;

    // reg-stage map (f32): 128 rows x 32 k, 16 elems/thread
    const int sr = tid >> 1, sc = (tid & 1) * 16, c0 = (tid & 1) * 2;
    // gload map: rows gr, gr+64; source chunk pre-swizzled
    const int gr = tid >> 2;
    const int gco = ((tid & 3) ^ ((gr >> 1) & 3)) * 8;
    const int wlds = (tid >> 6) * 512;

    const int l = tid & 63;
    const int wv = tid >> 6;
    const int wr = (wv >> 1) * 64, wc = (wv & 1) * 64;
    const int fr = l & 15, fq = l >> 4;

    f32x4 acc[4][4] = {};

    for (int k0 = 0; k0 < K; k0 += BKK) {
        // ---- stage A ----
        if (MODE == M_PROJ || MODE == M_PLAIN) {
            const float* s = Afs + z * aB + (long)(m0 + sr) * lda + k0 + sc;
            stage_sw<MODE == M_PROJ>(s, As[0], As[NS - 1], sr, c0);
        } else if (MODE == M_CONCAT) {
            if (k0 < K1) {
                const float* s = Afs + z * aB + (long)(m0 + sr) * lda + k0 + sc;
                stage_sw<false>(s, As[0], nullptr, sr, c0);
            } else {
                const bf16_t* s = A2b + z * a2B + (long)(m0 + gr) * lda2 + (k0 - K1) + gco;
                gload16(s, &As[0][wlds]);
                gload16(s + (long)64 * lda2, &As[0][2048 + wlds]);
            }
        } else { // M_SPLITB
            const bf16_t* s = Abh + z * aB + (long)(m0 + gr) * lda + k0 + gco;
            gload16(s, &As[0][wlds]);
            gload16(s + (long)64 * lda, &As[0][2048 + wlds]);
            gload16(s + loA, &As[NS - 1][wlds]);
            gload16(s + loA + (long)64 * lda, &As[NS - 1][2048 + wlds]);
        }
        // ---- stage B (always bf16 gload) ----
        {
            const bf16_t* s = Bbh + z * bB + (long)(n0 + gr) * ldb + k0 + gco;
            gload16(s, &Bs[0][wlds]);
            gload16(s + (long)64 * ldb, &Bs[0][2048 + wlds]);
            if (NS == 2) {
                gload16(s + loB, &Bs[NS - 1][wlds]);
                gload16(s + loB + (long)64 * ldb, &Bs[NS - 1][2048 + wlds]);
            }
        }
        __syncthreads();

        // ---- fragments (swizzled reads) + MFMA ----
        bf16x8 a_h[4], b_h[4], a_l[4], b_l[4];
        #pragma unroll
        for (int i = 0; i < 4; i++) {
            const int ra = wr + i * 16 + fr;
            const int rb = wc + i * 16 + fr;
            const int ka = (fq ^ ((ra >> 1) & 3)) * 8;
            const int kb = (fq ^ ((rb >> 1) & 3)) * 8;
            a_h[i] = *(const bf16x8*)&As[0][ra * 32 + ka];
            b_h[i] = *(const bf16x8*)&Bs[0][rb * 32 + kb];
            if (NS == 2) {
                a_l[i] = *(const bf16x8*)&As[NS - 1][ra * 32 + ka];
                b_l[i] = *(const bf16x8*)&Bs[NS - 1][rb * 32 + kb];
            }
        }
        #pragma unroll
        for (int mi = 0; mi < 4; mi++)
            #pragma unroll
            for (int ni = 0; ni < 4; ni++) {
                acc[mi][ni] = __builtin_amdgcn_mfma_f32_16x16x32_bf16(a_h[mi], b_h[ni], acc[mi][ni], 0, 0, 0);
                if (NS == 2) {
                    acc[mi][ni] = __builtin_amdgcn_mfma_f32_16x16x32_bf16(a_h[mi], b_l[ni], acc[mi][ni], 0, 0, 0);
                    acc[mi][ni] = __builtin_amdgcn_mfma_f32_16x16x32_bf16(a_l[mi], b_h[ni], acc[mi][ni], 0, 0, 0);
                }
            }
        __syncthreads();
    }

    // ---- epilogue ----
    if constexpr (OUTK == O_GSUM) {
        // masked row-sum: Gp[pc][b][z*512 + col] = sum_rows relu(acc+bias)*mask
        __shared__ float red[8][128];
        __shared__ int smask[128];
        const int* mrow = (z >= zalt) ? hmask : pmask;
        const int bb = m0 / 384;
        const int brow0 = m0 - bb * 384;
        if (tid < 128) smask[tid] = mrow[bb * 384 + brow0 + tid];
        __syncthreads();
        const int rid = (wv >> 1) * 4 + fq;
        #pragma unroll
        for (int ni = 0; ni < 4; ni++) {
            const int c = wc + ni * 16 + fr;
            const float bv = bias[n0 + c];
            float local = 0.f;
            #pragma unroll
            for (int mi = 0; mi < 4; mi++)
                #pragma unroll
                for (int j = 0; j < 4; j++) {
                    const int rloc = wr + mi * 16 + fq * 4 + j;
                    float v = fmaxf(acc[mi][ni][j] + bv, 0.f);
                    local += v * (float)smask[rloc];
                }
            red[rid][c] = local;
        }
        __syncthreads();
        if (tid < 128) {
            float s = 0.f;
            #pragma unroll
            for (int r = 0; r < 8; r++) s += red[r][tid];
            const int pc = (m0 >> 7) % 3;
            Cf[((long)pc * 32 + bb) * 1024 + z * 512 + n0 + tid] = s;
        }
    } else {
        #pragma unroll
        for (int ni = 0; ni < 4; ni++) {
            const int col = n0 + wc + ni * 16 + fr;
            const float bv = BIAS ? bias[col] : 0.f;
            #pragma unroll
            for (int mi = 0; mi < 4; mi++) {
                #pragma unroll
                for (int j = 0; j < 4; j++) {
                    const int row = m0 + wr + mi * 16 + fq * 4 + j;
                    float v = acc[mi][ni][j] + bv;
                    if (RELU) v = fmaxf(v, 0.f);
                    const long idx = z * cB + (long)row * ldc + col;
                    if (OUTK == O_F32) Cf[idx] = v;
                    else if (OUTK == O_BF16) Cb[idx] = (bf16_t)v;
                    else {
                        bf16_t h = (bf16_t)v;
                        Cb[idx] = h;
                        Cb[idx + loC] = (bf16_t)(v - (float)h);
                    }
                }
            }
        }
    }
}

// out[c][r] = bf16(in[r][c]) (+ optional lo split); z-select between in/in2
template<bool SPLIT>
__global__ __launch_bounds__(256) void transpose_kernel(
    const float* __restrict__ in, const float* __restrict__ in2, int zsplit,
    bf16_t* __restrict__ out, bf16_t* __restrict__ outLo,
    int R, int C, long inB, long outB)
{
    __shared__ float tile[32][33];
    const int z = blockIdx.z;
    const float* src = (z >= zsplit) ? (in2 + (long)(z - zsplit) * inB)
                                     : (in + (long)z * inB);
    const int x0 = blockIdx.x * 32, y0 = blockIdx.y * 32;
    const int tx = threadIdx.x & 31, ty = threadIdx.x >> 5;
    #pragma unroll
    for (int i = 0; i < 32; i += 8)
        tile[ty + i][tx] = src[(long)(y0 + ty + i) * C + x0 + tx];
    __syncthreads();
    bf16_t* dst = out + (long)z * outB;
    bf16_t* dstL = SPLIT ? (outLo + (long)z * outB) : nullptr;
    #pragma unroll
    for (int i = 0; i < 32; i += 8) {
        float v = tile[tx][ty + i];
        bf16_t h = (bf16_t)v;
        dst[(long)(x0 + ty + i) * R + y0 + tx] = h;
        if (SPLIT) dstL[(long)(x0 + ty + i) * R + y0 + tx] = (bf16_t)(v - (float)h);
    }
}

// Row-wise masked softmax over sim rows (AllenNLP legacy semantics).
__global__ __launch_bounds__(384) void masked_softmax_row(
    const float* __restrict__ S, const int* __restrict__ mask,
    float* __restrict__ out)
{
    const int row = blockIdx.x;        // b*384 + p
    const int b = row / 384;
    const int t = threadIdx.x;         // h
    __shared__ float redmax[6], redsum[6];

    float v = S[(long)row * 384 + t];
    int mm = mask[b * 384 + t];

    float x = mm ? v : -3.4e38f;
    #pragma unroll
    for (int o = 32; o > 0; o >>= 1) x = fmaxf(x, __shfl_xor(x, o, 64));
    int wid = t >> 6, lane = t & 63;
    if (lane == 0) redmax[wid] = x;
    __syncthreads();
    float mx = redmax[0];
    #pragma unroll
    for (int w = 1; w < 6; w++) mx = fmaxf(mx, redmax[w]);

    float e = mm ? expf(v - mx) : 0.f;
    float s = e;
    #pragma unroll
    for (int o = 32; o > 0; o >>= 1) s += __shfl_xor(s, o, 64);
    if (lane == 0) redsum[wid] = s;
    __syncthreads();
    float tot = 0.f;
    #pragma unroll
    for (int w = 0; w < 6; w++) tot += redsum[w];

    out[(long)row * 384 + t] = (tot > 0.f) ? e / tot : 0.f;
}

// Column softmax pass 1: max-then-sum. grid (6 hc, 32 b), block 256.
__global__ __launch_bounds__(256) void col_stats(
    const float* __restrict__ S, const int* __restrict__ mask,
    float* __restrict__ cmax, float* __restrict__ csum)
{
    __shared__ int pml[384];
    __shared__ float mred[4][64], sred[4][64];
    const int b = blockIdx.y;
    const int h0 = blockIdx.x * 64;
    const int t = threadIdx.x;
    const int tk = t >> 6, hh = t & 63;

    for (int i = t; i < 384; i += 256) pml[i] = mask[b * 384 + i];
    __syncthreads();

    const float* Sb = S + (long)b * SIM_B + h0 + hh;
    float m = -3.4e38f;
    for (int p = tk; p < 384; p += 4)
        if (pml[p]) m = fmaxf(m, Sb[(long)p * 384]);
    mred[tk][hh] = m;
    __syncthreads();
    const float M = fmaxf(fmaxf(mred[0][hh], mred[1][hh]),
                          fmaxf(mred[2][hh], mred[3][hh]));
    float s = 0.f;
    for (int p = tk; p < 384; p += 4)
        if (pml[p]) s += expf(Sb[(long)p * 384] - M);
    sred[tk][hh] = s;
    __syncthreads();
    if (t < 64) {
        const float Mf = fmaxf(fmaxf(mred[0][t], mred[1][t]),
                               fmaxf(mred[2][t], mred[3][t]));
        cmax[b * 384 + h0 + t] = Mf;
        csum[b * 384 + h0 + t] = sred[0][t] + sred[1][t] + sred[2][t] + sred[3][t];
    }
}

// Column softmax pass 2: fused transpose + normalize. out[b][h][p].
__global__ __launch_bounds__(256) void col_write(
    const float* __restrict__ S, const int* __restrict__ mask,
    const float* __restrict__ cmax, const float* __restrict__ csum,
    float* __restrict__ out)
{
    __shared__ float tile[32][33];
    const int b = blockIdx.z;
    const int h0 = blockIdx.x * 32, p0 = blockIdx.y * 32;
    const int tx = threadIdx.x & 31, ty = threadIdx.x >> 5;
    const float* src = S + (long)b * SIM_B;
    #pragma unroll
    for (int i = 0; i < 32; i += 8)
        tile[ty + i][tx] = src[(long)(p0 + ty + i) * 384 + h0 + tx];
    __syncthreads();
    const int pm_v = mask[b * 384 + p0 + tx];
    float* dst = out + (long)b * SIM_B;
    #pragma unroll
    for (int i = 0; i < 32; i += 8) {
        const int h = h0 + ty + i;
        const float mx = cmax[b * 384 + h];
        const float tot = csum[b * 384 + h];
        float v = tile[tx][ty + i];
        float r = (pm_v && tot > 0.f) ? expf(v - mx) / tot : 0.f;
        dst[(long)h * 384 + p0 + tx] = r;
    }
}

// hidden = relu(G @ W1 + b1), combining 3 p-chunk partials. grid (8 jc, 32 b)
__global__ __launch_bounds__(256) void hidden_kernel(
    const float* __restrict__ Gp, const float* __restrict__ W1,
    const float* __restrict__ b1, float* __restrict__ Hbuf)
{
    __shared__ float g[1024];
    __shared__ float part[4][64];
    const int b = blockIdx.y, j0 = blockIdx.x * 64;
    const int t = threadIdx.x;
    for (int i = t; i < 1024; i += 256)
        g[i] = Gp[((long)0 * 32 + b) * 1024 + i] + Gp[((long)1 * 32 + b) * 1024 + i]
             + Gp[((long)2 * 32 + b) * 1024 + i];
    __syncthreads();
    const int tj = t & 63, tk = t >> 6;
    const float* w = W1 + (long)(tk * 256) * 512 + j0 + tj;
    const float* gk = g + tk * 256;
    float acc = 0.f;
    #pragma unroll 8
    for (int k = 0; k < 256; k++)
        acc = fmaf(gk[k], w[(long)k * 512], acc);
    part[tk][tj] = acc;
    __syncthreads();
    if (t < 64) {
        float v = part[0][t] + part[1][t] + part[2][t] + part[3][t] + b1[j0 + t];
        Hbuf[(long)b * 512 + j0 + t] = fmaxf(v, 0.f);
    }
}

// logits + probs: grid 32, block 64
__global__ __launch_bounds__(64) void logits_kernel(
    const float* __restrict__ Hbuf, const float* __restrict__ W2,
    const float* __restrict__ b2, float* __restrict__ out)
{
    const int b = blockIdx.x, l = threadIdx.x;
    const float* h = Hbuf + (long)b * 512;
    float a0 = 0.f, a1 = 0.f, a2 = 0.f;
    #pragma unroll
    for (int k = l; k < 512; k += 64) {
        float hv = h[k];
        a0 = fmaf(hv, W2[k * 3 + 0], a0);
        a1 = fmaf(hv, W2[k * 3 + 1], a1);
        a2 = fmaf(hv, W2[k * 3 + 2], a2);
    }
    #pragma unroll
    for (int o = 32; o > 0; o >>= 1) {
        a0 += __shfl_xor(a0, o, 64);
        a1 += __shfl_xor(a1, o, 64);
        a2 += __shfl_xor(a2, o, 64);
    }
    if (l == 0) {
        float l0 = a0 + b2[0], l1 = a1 + b2[1], l2 = a2 + b2[2];
        float mx = fmaxf(l0, fmaxf(l1, l2));
        float e0 = expf(l0 - mx), e1 = expf(l1 - mx), e2 = expf(l2 - mx);
        float s = e0 + e1 + e2;
        out[OUT_LOGITS + b * 3 + 0] = l0;
        out[OUT_LOGITS + b * 3 + 1] = l1;
        out[OUT_LOGITS + b * 3 + 2] = l2;
        out[OUT_PROBS + b * 3 + 0] = e0 / s;
        out[OUT_PROBS + b * 3 + 1] = e1 / s;
        out[OUT_PROBS + b * 3 + 2] = e2 / s;
    }
}

extern "C" void kernel_launch(void* const* d_in, const int* in_sizes, int n_in,
                              void* d_out, int out_size, void* d_ws, size_t ws_size,
                              hipStream_t stream) {
    const float* emb_p = (const float*)d_in[0];
    const float* emb_h = (const float*)d_in[1];
    const int* pm = (const int*)d_in[2];
    const int* hm = (const int*)d_in[3];
    const float* Wa = (const float*)d_in[4];
    const float* ba = (const float*)d_in[5];
    const float* Wc = (const float*)d_in[6];
    const float* bc = (const float*)d_in[7];
    const float* W1 = (const float*)d_in[8];
    const float* b1 = (const float*)d_in[9];
    const float* W2 = (const float*)d_in[10];
    const float* b2 = (const float*)d_in[11];
    float* out = (float*)d_out;
    char* W = (char*)d_ws;

    bf16_t* WaTh  = (bf16_t*)(W + OFF_WATH);   // [512a][512d] hi
    bf16_t* WaTl  = (bf16_t*)(W + OFF_WATL);   // lo
    bf16_t* WcT   = (bf16_t*)(W + OFF_WCT);    // [512n][1024k]
    bf16_t* A     = (bf16_t*)(W + OFF_A);      // 50 MB region
    float*  sim   = (float*)(W + OFF_SIM);
    float*  cmaxb = (float*)(W + OFF_CM);
    float*  csumb = (float*)(W + OFF_CS);
    float*  Gp    = (float*)(W + OFF_GP);      // [3][32][1024] f32
    float*  Hbuf  = (float*)(W + OFF_H);
    // region-A aliases (lifetime-disjoint)
    bf16_t* projs  = A;                        // [hi_p|lo_p|hi_h|lo_h] x 6291456
    bf16_t* embT   = A;                        // [64][512][384] (p batches 0-31, h 32-63)
    bf16_t* attAll = A + ATT_ALL_E;            // [64][384][512] (attp 0-31, atth 32-63)

    // 0: weight transposes (WaT split bf16, WcT bf16)
    transpose_kernel<true><<<dim3(16, 16, 1), 256, 0, stream>>>(
        Wa, nullptr, 999, WaTh, WaTl, 512, 512, 0, 0);
    transpose_kernel<false><<<dim3(16, 32, 1), 256, 0, stream>>>(
        Wc, nullptr, 999, WcT, nullptr, 1024, 512, 0, 0);

    // 1: proj merged (z=0 premise, z=1 hypothesis), split bf16 output
    mgemm<M_PROJ, O_SPLIT, true, true><<<dim3(4, 96, 2), 256, 0, stream>>>(
        emb_p, emb_h, 1, nullptr, 0, nullptr, 0, WaTh, 262144L, ba,
        nullptr, nullptr,
        nullptr, projs, PROJ_LO,
        512, 0, 0L, 0L, PROJ_Z, 512, 0, 512, 512);

    // 2: sim (batched NT, hi/lo 3-pass, all-gload staging)
    mgemm<M_SPLITB, O_F32, false, false><<<dim3(3, 3, 32), 256, 0, stream>>>(
        nullptr, nullptr, 999, projs, PROJ_LO, nullptr, 0,
        projs + PROJ_Z, PROJ_LO, nullptr,
        nullptr, nullptr,
        sim, nullptr, 0,
        512, 0, (long)EMB_B, (long)EMB_B, (long)SIM_B, 512, 0, 512, 384);

    // 3: p2h row softmax -> d_out
    masked_softmax_row<<<NPH, 384, 0, stream>>>(sim, hm, out + OUT_P2H);
    // 4: h2p column softmax (stats + fused transpose write)
    col_stats<<<dim3(6, 32), 256, 0, stream>>>(sim, pm, cmaxb, csumb);
    col_write<<<dim3(12, 12, 32), 256, 0, stream>>>(sim, pm, cmaxb, csumb, out + OUT_H2P);

    // 5: emb transposes merged -> embT (z<32: emb_p, z>=32: emb_h)
    transpose_kernel<false><<<dim3(16, 12, 64), 256, 0, stream>>>(
        emb_p, emb_h, 32, embT, nullptr, 384, 512, (long)EMB_B, (long)EMB_B);

    // 6: attention apply merged: z<32: attp = h2p@embTp ; z>=32: atth = p2h@embTh
    mgemm<M_PLAIN, O_BF16, false, false><<<dim3(4, 3, 64), 256, 0, stream>>>(
        out + OUT_H2P, nullptr, 1 << 30, nullptr, 0, nullptr, 0,
        embT, 0, nullptr,
        nullptr, nullptr,
        nullptr, attAll, 0,
        384, 0, (long)SIM_B, (long)EMB_B, (long)EMB_B, 384, 0, 384, 512);

    // 7: cmp merged + fused masked row-sum -> Gp partials (no cmp store)
    //    z=0: relu(cat(emb_p, atth)@Wc+bc) . pm ; z=1: cat(emb_h, attp) . hm
    mgemm<M_CONCAT, O_GSUM, true, true><<<dim3(4, 96, 2), 256, 0, stream>>>(
        emb_p, emb_h, 1, nullptr, 0,
        attAll + CMP_Z, -(long)CMP_Z,       // z=0 -> atth, z=1 -> attp
        WcT, 0, bc,
        pm, hm,
        Gp, nullptr, 0,
        1024, 512, 0L, 0L, 0L, 512, 512, 1024, 512);

    // 8: aggregate MLP + softmax
    hidden_kernel<<<dim3(8, 32), 256, 0, stream>>>(Gp, W1, b1, Hbuf);
    logits_kernel<<<32, 64, 0, stream>>>(Hbuf, W2, b2, out);
}